// Round 1
// baseline (210.432 us; speedup 1.0000x reference)
//
#include <hip/hip_runtime.h>
#include <math.h>

// ---------------------------------------------------------------------------
// QCNN_Diff: 8-qubit statevector sim, B=32768, 3 branches (rx/ry/rz CR gates),
// expval_z features -> tiny MLP. One wave (64 lanes) per batch element;
// 4 complex amplitudes per lane. Qubit->bit map chosen so qubits 3 and 7
// (the hot targets + the measured wires) are the in-lane bits (0,1):
//   bitpos[q] : q0->7 q1->6 q2->5 q3->0 q4->4 q5->3 q6->2 q7->1
// Cross-lane pairing via __shfl_xor(1<<(bit-2)).
// Gate matrices precomputed into d_ws by a 48-thread prep kernel.
// ---------------------------------------------------------------------------

template <int BT, int BC>
__device__ __forceinline__ void gate(float2 w[4], const float* __restrict__ U,
                                     int lane) {
  const float u00r = U[0], u00i = U[1];
  const float u01r = U[2], u01i = U[3];
  const float u10r = U[4], u10i = U[5];
  const float u11r = U[6], u11i = U[7];
  if constexpr (BT >= 2) {
    constexpr int mask = 1 << (BT - 2);
#pragma unroll
    for (int k = 0; k < 4; ++k) {
      const float pr = __shfl_xor(w[k].x, mask, 64);
      const float pi = __shfl_xor(w[k].y, mask, 64);
      const int i = (lane << 2) | k;
      const int tb = (i >> BT) & 1;
      const float uar = tb ? u11r : u00r;
      const float uai = tb ? u11i : u00i;
      const float ubr = tb ? u10r : u01r;
      const float ubi = tb ? u10i : u01i;
      const float nr = uar * w[k].x - uai * w[k].y + ubr * pr - ubi * pi;
      const float ni = uar * w[k].y + uai * w[k].x + ubr * pi + ubi * pr;
      const bool on = (BC < 0) || (((i >> BC) & 1) != 0);
      w[k].x = on ? nr : w[k].x;
      w[k].y = on ? ni : w[k].y;
    }
  } else {
    float2 ow[4];
#pragma unroll
    for (int k = 0; k < 4; ++k) ow[k] = w[k];
#pragma unroll
    for (int k = 0; k < 4; ++k) {
      const float2 p = ow[k ^ (1 << BT)];
      const int i = (lane << 2) | k;
      const int tb = (i >> BT) & 1;  // compile-time: depends only on k
      const float uar = tb ? u11r : u00r;
      const float uai = tb ? u11i : u00i;
      const float ubr = tb ? u10r : u01r;
      const float ubi = tb ? u10i : u01i;
      const float nr = uar * ow[k].x - uai * ow[k].y + ubr * p.x - ubi * p.y;
      const float ni = uar * ow[k].y + uai * ow[k].x + ubr * p.y + ubi * p.x;
      const bool on = (BC < 0) || (((i >> BC) & 1) != 0);
      w[k].x = on ? nr : w[k].x;
      w[k].y = on ? ni : w[k].y;
    }
  }
}

// 48 gate matrices: [branch(3)][gate(16)][2x2 complex = 8 floats]
__global__ void qcnn_prep(const float* __restrict__ crx,
                          const float* __restrict__ u3x,
                          const float* __restrict__ cry,
                          const float* __restrict__ u3y,
                          const float* __restrict__ crz,
                          const float* __restrict__ u3z,
                          float* __restrict__ G) {
  const int tid = threadIdx.x;
  if (tid >= 48) return;
  const int br = tid >> 4;
  const int g = tid & 15;
  const float* crp = (br == 0) ? crx : (br == 1) ? cry : crz;
  const float* u3p = (br == 0) ? u3x : (br == 1) ? u3y : u3z;

  float m[8];
  int u3i = -1;
  float th = 0.f;
  if (g < 7)
    th = crp[g];
  else if (g < 11)
    u3i = g - 7;
  else if (g < 14)
    th = crp[7 + (g - 11)];
  else
    u3i = 4 + (g - 14);

  if (u3i < 0) {
    float s, c;
    sincosf(0.5f * th, &s, &c);
    if (br == 0) {  // rx: [[c, -is],[-is, c]]
      m[0] = c;  m[1] = 0.f; m[2] = 0.f; m[3] = -s;
      m[4] = 0.f; m[5] = -s; m[6] = c;  m[7] = 0.f;
    } else if (br == 1) {  // ry: [[c, -s],[s, c]]
      m[0] = c;  m[1] = 0.f; m[2] = -s; m[3] = 0.f;
      m[4] = s;  m[5] = 0.f; m[6] = c;  m[7] = 0.f;
    } else {  // rz: diag(e^{-i th/2}, e^{i th/2})
      m[0] = c;  m[1] = -s;  m[2] = 0.f; m[3] = 0.f;
      m[4] = 0.f; m[5] = 0.f; m[6] = c;  m[7] = s;
    }
  } else {
    const float t0 = u3p[u3i * 3 + 0];
    const float ph = u3p[u3i * 3 + 1];
    const float lm = u3p[u3i * 3 + 2];
    float st, ct, sp, cp, sl, cl;
    sincosf(0.5f * t0, &st, &ct);
    sincosf(ph, &sp, &cp);
    sincosf(lm, &sl, &cl);
    m[0] = ct;       m[1] = 0.f;
    m[2] = -cl * st; m[3] = -sl * st;
    m[4] = cp * st;  m[5] = sp * st;
    const float cpl = cp * cl - sp * sl;
    const float spl = sp * cl + cp * sl;
    m[6] = cpl * ct; m[7] = spl * ct;
  }
#pragma unroll
  for (int j = 0; j < 8; ++j) G[tid * 8 + j] = m[j];
}

__global__ __launch_bounds__(256) void qcnn_main(
    const float* __restrict__ x, const float* __restrict__ G,
    const float* __restrict__ w1, const float* __restrict__ b1,
    const float* __restrict__ w2, const float* __restrict__ b2,
    float* __restrict__ out, int B) {
  const int gtid = blockIdx.x * blockDim.x + threadIdx.x;
  const int b = gtid >> 6;
  const int lane = threadIdx.x & 63;
  if (b >= B) return;

  constexpr int bitpos[8] = {7, 6, 5, 0, 4, 3, 2, 1};

  // encode: product state, real amplitudes
  float enc[4] = {1.f, 1.f, 1.f, 1.f};
#pragma unroll
  for (int q = 0; q < 8; ++q) {
    const float xv = x[b * 8 + q];
    float s, c;
    __sincosf(0.5f * xv, &s, &c);
    const int bp = bitpos[q];
#pragma unroll
    for (int k = 0; k < 4; ++k) {
      const int i = (lane << 2) | k;
      enc[k] *= ((i >> bp) & 1) ? s : c;
    }
  }

  float f[6];
#pragma unroll
  for (int br = 0; br < 3; ++br) {
    const float* Gb = G + br * 128;
    float2 w[4];
#pragma unroll
    for (int k = 0; k < 4; ++k) w[k] = make_float2(enc[k], 0.f);

    // CR_PAIRS_1: (0,1)(2,3)(4,5)(6,7)(1,2)(3,4)(5,6) -> <bt,bc>
    gate<6, 7>(w, Gb + 0, lane);
    gate<0, 5>(w, Gb + 8, lane);
    gate<3, 4>(w, Gb + 16, lane);
    gate<1, 2>(w, Gb + 24, lane);
    gate<5, 6>(w, Gb + 32, lane);
    gate<4, 0>(w, Gb + 40, lane);
    gate<2, 3>(w, Gb + 48, lane);
    // U3 on wires 1,3,5,7
    gate<6, -1>(w, Gb + 56, lane);
    gate<0, -1>(w, Gb + 64, lane);
    gate<3, -1>(w, Gb + 72, lane);
    gate<1, -1>(w, Gb + 80, lane);
    // CR_PAIRS_2: (1,3)(5,7)(3,5)
    gate<0, 6>(w, Gb + 88, lane);
    gate<1, 3>(w, Gb + 96, lane);
    gate<3, 0>(w, Gb + 104, lane);
    // U3 on 3, then 7
    gate<0, -1>(w, Gb + 112, lane);
    gate<1, -1>(w, Gb + 120, lane);

    // expval_z(3) -> i-bit0, expval_z(7) -> i-bit1
    float z3 = 0.f, z7 = 0.f;
#pragma unroll
    for (int k = 0; k < 4; ++k) {
      const float p = w[k].x * w[k].x + w[k].y * w[k].y;
      z3 += (k & 1) ? -p : p;
      z7 += (k & 2) ? -p : p;
    }
#pragma unroll
    for (int m = 1; m < 64; m <<= 1) {
      z3 += __shfl_xor(z3, m, 64);
      z7 += __shfl_xor(z7, m, 64);
    }
    f[br * 2 + 0] = z3;
    f[br * 2 + 1] = z7;
  }

  // MLP head: h = tanh(f @ w1.T + b1); out = sigmoid(h @ w2.T + b2)
  float acc2 = b2[0];
#pragma unroll
  for (int j = 0; j < 12; ++j) {
    float a = b1[j];
#pragma unroll
    for (int k = 0; k < 6; ++k) a += w1[j * 6 + k] * f[k];
    acc2 += w2[j] * tanhf(a);
  }
  const float res = 1.f / (1.f + __expf(-acc2));
  if (lane == 0) out[b] = res;
}

extern "C" void kernel_launch(void* const* d_in, const int* in_sizes, int n_in,
                              void* d_out, int out_size, void* d_ws,
                              size_t ws_size, hipStream_t stream) {
  const float* x = (const float*)d_in[0];
  const float* crx = (const float*)d_in[1];
  const float* u3x = (const float*)d_in[2];
  const float* cry = (const float*)d_in[3];
  const float* u3y = (const float*)d_in[4];
  const float* crz = (const float*)d_in[5];
  const float* u3z = (const float*)d_in[6];
  const float* w1 = (const float*)d_in[7];
  const float* b1 = (const float*)d_in[8];
  const float* w2 = (const float*)d_in[9];
  const float* b2 = (const float*)d_in[10];
  float* out = (float*)d_out;
  float* G = (float*)d_ws;  // 384 floats
  const int B = in_sizes[0] / 8;

  hipLaunchKernelGGL(qcnn_prep, dim3(1), dim3(64), 0, stream, crx, u3x, cry,
                     u3y, crz, u3z, G);
  const int threads = 256;
  const int blocks = (B * 64 + threads - 1) / threads;
  hipLaunchKernelGGL(qcnn_main, dim3(blocks), dim3(threads), 0, stream, x, G,
                     w1, b1, w2, b2, out, B);
}

// Round 2
// 140.089 us; speedup vs baseline: 1.5021x; 1.5021x over previous
//
#include <hip/hip_runtime.h>
#include <math.h>

// ---------------------------------------------------------------------------
// QCNN_Diff R2: one wave per batch element, 4 complex amps/lane as v2f(re,im),
// packed-fp32 math (v_pk_fma_f32), gate kind specialization:
//   CRX: symmetric -> no target-bit select; control folded into (c,s)
//   CRY: real -> sign select on s only
//   CRZ: diagonal -> NO shuffles at all
//   U3 : general 2x2, 4 packed fma/amp
// bitpos[q]: q0->7 q1->6 q2->5 q3->0 q4->4 q5->3 q6->2 q7->1  (qubits 3,7 are
// the in-lane bits so the measured wires + 8/16 gates need no cross-lane).
// ---------------------------------------------------------------------------

typedef float v2f __attribute__((ext_vector_type(2)));

__device__ __forceinline__ v2f mk2(float a, float b) { v2f r; r.x = a; r.y = b; return r; }
__device__ __forceinline__ v2f spl(float a) { v2f r; r.x = a; r.y = a; return r; }
__device__ __forceinline__ v2f shfl2(v2f v, int m) {
  v2f r;
  r.x = __shfl_xor(v.x, m, 64);
  r.y = __shfl_xor(v.y, m, 64);
  return r;
}

// KIND: 0=RX, 1=RY, 2=RZ. BT/BC = target/control bit in amplitude index
// (bits 0..1 = in-lane k, bits 2..7 = lane bits). U[0]=cos(t/2), U[1]=sin(t/2).
template <int KIND, int BT, int BC>
__device__ __forceinline__ void crg(v2f w[4], const float* __restrict__ U, int lane) {
  const float c = U[0], s = U[1];
  float cc = c, ss = s;
  if constexpr (BC >= 2) {
    const bool on = (lane >> (BC - 2)) & 1;
    cc = on ? c : 1.f;
    ss = on ? s : 0.f;
  }
  if constexpr (KIND == 2) {
    // rz: diag(e^{-it/2}, e^{it/2}) -> w' = cc*w + st*(w.y, -w.x), st=tb?-ss:ss
    float stl = ss;
    if constexpr (BT >= 2) {
      const bool tb = (lane >> (BT - 2)) & 1;
      stl = tb ? -ss : ss;
    }
#pragma unroll
    for (int k = 0; k < 4; ++k) {
      const bool kon = (BC >= 2) || (((k >> BC) & 1) != 0);
      if (!kon) continue;
      float st = stl;
      if constexpr (BT < 2) st = ((k >> BT) & 1) ? -ss : ss;
      const v2f t = mk2(w[k].y, -w[k].x);
      w[k] = spl(cc) * w[k] + spl(st) * t;
    }
  } else {
    v2f ow[4];
    if constexpr (BT < 2) {
#pragma unroll
      for (int k = 0; k < 4; ++k) ow[k] = w[k];
    }
    float stl = ss;
    if constexpr (KIND == 1 && BT >= 2) {
      const bool tb = (lane >> (BT - 2)) & 1;
      stl = tb ? ss : -ss;
    }
#pragma unroll
    for (int k = 0; k < 4; ++k) {
      const bool kon = (BC >= 2) || (((k >> BC) & 1) != 0);
      if (!kon) continue;
      v2f p;
      if constexpr (BT >= 2)
        p = shfl2(w[k], 1 << (BT - 2));
      else
        p = ow[k ^ (1 << BT)];
      if constexpr (KIND == 0) {
        // rx: [[c,-is],[-is,c]] (symmetric): w' = cc*w + ss*(p.y, -p.x)
        const v2f t = mk2(p.y, -p.x);
        w[k] = spl(cc) * w[k] + spl(ss) * t;
      } else {
        // ry: [[c,-s],[s,c]]: w' = cc*w + st*p, st = tb? ss : -ss
        float st = stl;
        if constexpr (BT < 2) st = ((k >> BT) & 1) ? ss : -ss;
        w[k] = spl(cc) * w[k] + spl(st) * p;
      }
    }
  }
}

// general u3; U = (u00r,u00i, u01r,u01i, u10r,u10i, u11r,u11i), u00i == 0
template <int BT>
__device__ __forceinline__ void u3g(v2f w[4], const float* __restrict__ U, int lane) {
  const float ar = U[0], ai = U[1], br = U[2], bi = U[3];
  const float cr = U[4], ci = U[5], dr = U[6], di = U[7];
  if constexpr (BT >= 2) {
    const bool tb = (lane >> (BT - 2)) & 1;
    const float uar = tb ? dr : ar;
    const float uai = tb ? di : ai;
    const float ubr = tb ? cr : br;
    const float ubi = tb ? ci : bi;
#pragma unroll
    for (int k = 0; k < 4; ++k) {
      const v2f p = shfl2(w[k], 1 << (BT - 2));
      const v2f iw = mk2(-w[k].y, w[k].x);
      const v2f ip = mk2(-p.y, p.x);
      w[k] = spl(uar) * w[k] + spl(uai) * iw + spl(ubr) * p + spl(ubi) * ip;
    }
  } else {
    v2f ow[4];
#pragma unroll
    for (int k = 0; k < 4; ++k) ow[k] = w[k];
#pragma unroll
    for (int k = 0; k < 4; ++k) {
      const v2f p = ow[k ^ (1 << BT)];
      const v2f ip = mk2(-p.y, p.x);
      if (((k >> BT) & 1) == 0) {
        // row0: u00 real -> 3 packed ops
        w[k] = spl(ar) * ow[k] + spl(br) * p + spl(bi) * ip;
      } else {
        const v2f iw = mk2(-ow[k].y, ow[k].x);
        w[k] = spl(dr) * ow[k] + spl(di) * iw + spl(cr) * p + spl(ci) * ip;
      }
    }
  }
}

template <int KIND>
__device__ __forceinline__ v2f run_branch(const float enc[4], const float* __restrict__ Gb,
                                          int lane) {
  v2f w[4];
#pragma unroll
  for (int k = 0; k < 4; ++k) w[k] = mk2(enc[k], 0.f);
  // CR_PAIRS_1: (0,1)(2,3)(4,5)(6,7)(1,2)(3,4)(5,6) -> <BT,BC>
  crg<KIND, 6, 7>(w, Gb + 0, lane);
  crg<KIND, 0, 5>(w, Gb + 8, lane);
  crg<KIND, 3, 4>(w, Gb + 16, lane);
  crg<KIND, 1, 2>(w, Gb + 24, lane);
  crg<KIND, 5, 6>(w, Gb + 32, lane);
  crg<KIND, 4, 0>(w, Gb + 40, lane);
  crg<KIND, 2, 3>(w, Gb + 48, lane);
  // U3 on wires 1,3,5,7 -> BT 6,0,3,1
  u3g<6>(w, Gb + 56, lane);
  u3g<0>(w, Gb + 64, lane);
  u3g<3>(w, Gb + 72, lane);
  u3g<1>(w, Gb + 80, lane);
  // CR_PAIRS_2: (1,3)(5,7)(3,5)
  crg<KIND, 0, 6>(w, Gb + 88, lane);
  crg<KIND, 1, 3>(w, Gb + 96, lane);
  crg<KIND, 3, 0>(w, Gb + 104, lane);
  // U3 on 3, then 7
  u3g<0>(w, Gb + 112, lane);
  u3g<1>(w, Gb + 120, lane);

  // expval_z(3) -> amp bit0, expval_z(7) -> amp bit1
  v2f z = mk2(0.f, 0.f);
#pragma unroll
  for (int k = 0; k < 4; ++k) {
    const float p = w[k].x * w[k].x + w[k].y * w[k].y;
    z.x += (k & 1) ? -p : p;
    z.y += (k & 2) ? -p : p;
  }
#pragma unroll
  for (int m = 1; m < 64; m <<= 1) z += shfl2(z, m);
  return z;
}

// 48 gate slots x 8 floats: CR slots hold (c,s); U3 slots hold full 2x2 complex
__global__ void qcnn_prep(const float* __restrict__ crx, const float* __restrict__ u3x,
                          const float* __restrict__ cry, const float* __restrict__ u3y,
                          const float* __restrict__ crz, const float* __restrict__ u3z,
                          float* __restrict__ G) {
  const int tid = threadIdx.x;
  if (tid >= 48) return;
  const int br = tid >> 4;
  const int g = tid & 15;
  const float* crp = (br == 0) ? crx : (br == 1) ? cry : crz;
  const float* u3p = (br == 0) ? u3x : (br == 1) ? u3y : u3z;

  float m[8] = {0.f, 0.f, 0.f, 0.f, 0.f, 0.f, 0.f, 0.f};
  int u3i = -1;
  float th = 0.f;
  if (g < 7)
    th = crp[g];
  else if (g < 11)
    u3i = g - 7;
  else if (g < 14)
    th = crp[7 + (g - 11)];
  else
    u3i = 4 + (g - 14);

  if (u3i < 0) {
    float s, c;
    sincosf(0.5f * th, &s, &c);
    m[0] = c;
    m[1] = s;
  } else {
    const float t0 = u3p[u3i * 3 + 0];
    const float ph = u3p[u3i * 3 + 1];
    const float lm = u3p[u3i * 3 + 2];
    float st, ct, sp, cp, sl, cl;
    sincosf(0.5f * t0, &st, &ct);
    sincosf(ph, &sp, &cp);
    sincosf(lm, &sl, &cl);
    m[0] = ct;        m[1] = 0.f;
    m[2] = -cl * st;  m[3] = -sl * st;
    m[4] = cp * st;   m[5] = sp * st;
    const float cpl = cp * cl - sp * sl;
    const float spl_ = sp * cl + cp * sl;
    m[6] = cpl * ct;  m[7] = spl_ * ct;
  }
#pragma unroll
  for (int j = 0; j < 8; ++j) G[tid * 8 + j] = m[j];
}

__global__ __launch_bounds__(256) void qcnn_main(
    const float* __restrict__ x, const float* __restrict__ G,
    const float* __restrict__ w1, const float* __restrict__ b1,
    const float* __restrict__ w2, const float* __restrict__ b2,
    float* __restrict__ out, int B) {
  const int gtid = blockIdx.x * blockDim.x + threadIdx.x;
  const int b = gtid >> 6;
  const int lane = threadIdx.x & 63;
  if (b >= B) return;

  // ---- encode: product state, real amplitudes ----
  const float4* xv = reinterpret_cast<const float4*>(x + b * 8);
  const float4 xlo = xv[0], xhi = xv[1];
  const float xq[8] = {xlo.x, xlo.y, xlo.z, xlo.w, xhi.x, xhi.y, xhi.z, xhi.w};
  float sn[8], cs[8];
#pragma unroll
  for (int q = 0; q < 8; ++q) __sincosf(0.5f * xq[q], &sn[q], &cs[q]);
  // lane-bit qubits: q0->b7 q1->b6 q2->b5 q4->b4 q5->b3 q6->b2 (lane bit = bp-2)
  float P = 1.f;
  {
    const int qH[6] = {0, 1, 2, 4, 5, 6};
    const int bH[6] = {7, 6, 5, 4, 3, 2};
#pragma unroll
    for (int t = 0; t < 6; ++t)
      P *= ((lane >> (bH[t] - 2)) & 1) ? sn[qH[t]] : cs[qH[t]];
  }
  float enc[4];
#pragma unroll
  for (int k = 0; k < 4; ++k)
    enc[k] = P * ((k & 1) ? sn[3] : cs[3]) * ((k & 2) ? sn[7] : cs[7]);

  const v2f fx = run_branch<0>(enc, G, lane);
  const v2f fy = run_branch<1>(enc, G + 128, lane);
  const v2f fz = run_branch<2>(enc, G + 256, lane);

  // ---- MLP head, lane-parallel over the 12 hidden units ----
  const int j = (lane < 12) ? lane : 0;
  const float* w1r = w1 + j * 6;
  float a = b1[j];
  a += w1r[0] * fx.x + w1r[1] * fx.y + w1r[2] * fy.x + w1r[3] * fy.y +
       w1r[4] * fz.x + w1r[5] * fz.y;
  // tanh(a) = 1 - 2/(exp(2a)+1)
  const float e = __expf(2.f * a);
  const float th = 1.f - 2.f * __builtin_amdgcn_rcpf(e + 1.f);
  float t = (lane < 12) ? w2[j] * th : 0.f;
#pragma unroll
  for (int m = 1; m < 64; m <<= 1) t += __shfl_xor(t, m, 64);
  const float acc = t + b2[0];
  const float res = __builtin_amdgcn_rcpf(1.f + __expf(-acc));
  if (lane == 0) out[b] = res;
}

extern "C" void kernel_launch(void* const* d_in, const int* in_sizes, int n_in,
                              void* d_out, int out_size, void* d_ws,
                              size_t ws_size, hipStream_t stream) {
  const float* x = (const float*)d_in[0];
  const float* crx = (const float*)d_in[1];
  const float* u3x = (const float*)d_in[2];
  const float* cry = (const float*)d_in[3];
  const float* u3y = (const float*)d_in[4];
  const float* crz = (const float*)d_in[5];
  const float* u3z = (const float*)d_in[6];
  const float* w1 = (const float*)d_in[7];
  const float* b1 = (const float*)d_in[8];
  const float* w2 = (const float*)d_in[9];
  const float* b2 = (const float*)d_in[10];
  float* out = (float*)d_out;
  float* G = (float*)d_ws;  // 384 floats
  const int B = in_sizes[0] / 8;

  hipLaunchKernelGGL(qcnn_prep, dim3(1), dim3(64), 0, stream, crx, u3x, cry,
                     u3y, crz, u3z, G);
  const int threads = 256;
  const int blocks = (B * 64 + threads - 1) / threads;
  hipLaunchKernelGGL(qcnn_main, dim3(blocks), dim3(threads), 0, stream, x, G,
                     w1, b1, w2, b2, out, B);
}

// Round 3
// 135.754 us; speedup vs baseline: 1.5501x; 1.0319x over previous
//
#include <hip/hip_runtime.h>
#include <math.h>

// ---------------------------------------------------------------------------
// QCNN_Diff R3: one wave per batch element, 4 complex amps/lane as VGPR pairs.
// All gate math via hand-written VOP3P packed-fp32 inline asm so that
// swap/negate/broadcast fold into op_sel/neg modifiers:
//   CR gates: exactly 2 v_pk ops per amplitude, U3: 4 (3 for real row0).
// Coefficient pair K=(c,s): control fold + target-sign fold done once per
// gate with cndmasks; op_sel picks .lo (c) or .hi (s) per instruction.
// bit map: q0->b7 q1->b6 q2->b5 q3->b0 q4->b4 q5->b3 q6->b2 q7->b1
// (amp index bits 0..1 = in-lane k, bits 2..7 = lane bits).
// ---------------------------------------------------------------------------

typedef float v2f __attribute__((ext_vector_type(2)));

// d = (a.lo*b.lo, a.lo*b.hi)            -- scalar-from-lo times pair
__device__ __forceinline__ v2f pk_mul_s(v2f a, v2f b) {
  v2f d;
  asm("v_pk_mul_f32 %0, %1, %2 op_sel:[0,0] op_sel_hi:[0,1]"
      : "=v"(d) : "v"(a), "v"(b));
  return d;
}
// d = (a.lo*b.lo + c.lo, a.lo*b.hi + c.hi)
__device__ __forceinline__ v2f pk_fma_slo(v2f a, v2f b, v2f c) {
  v2f d;
  asm("v_pk_fma_f32 %0, %1, %2, %3 op_sel:[0,0,0] op_sel_hi:[0,1,1]"
      : "=v"(d) : "v"(a), "v"(b), "v"(c));
  return d;
}
// d = (a.hi*b.lo + c.lo, a.hi*b.hi + c.hi)
__device__ __forceinline__ v2f pk_fma_shi(v2f a, v2f b, v2f c) {
  v2f d;
  asm("v_pk_fma_f32 %0, %1, %2, %3 op_sel:[1,0,0] op_sel_hi:[1,1,1]"
      : "=v"(d) : "v"(a), "v"(b), "v"(c));
  return d;
}
// d = (-a.hi*b.lo + c.lo, -a.hi*b.hi + c.hi)
__device__ __forceinline__ v2f pk_fma_shi_neg(v2f a, v2f b, v2f c) {
  v2f d;
  asm("v_pk_fma_f32 %0, %1, %2, %3 op_sel:[1,0,0] op_sel_hi:[1,1,1] neg_lo:[1,0,0] neg_hi:[1,0,0]"
      : "=v"(d) : "v"(a), "v"(b), "v"(c));
  return d;
}
// d = (a.hi*b.hi + c.lo, -a.hi*b.lo + c.hi)   -- "+s * (im,-re)"
__device__ __forceinline__ v2f pk_fma_rot(v2f a, v2f b, v2f c) {
  v2f d;
  asm("v_pk_fma_f32 %0, %1, %2, %3 op_sel:[1,1,0] op_sel_hi:[1,0,1] neg_hi:[0,1,0]"
      : "=v"(d) : "v"(a), "v"(b), "v"(c));
  return d;
}
// d = (-a.hi*b.hi + c.lo, a.hi*b.lo + c.hi)   -- "+s * i*(re,im)"
__device__ __forceinline__ v2f pk_fma_irot(v2f a, v2f b, v2f c) {
  v2f d;
  asm("v_pk_fma_f32 %0, %1, %2, %3 op_sel:[1,1,0] op_sel_hi:[1,0,1] neg_lo:[0,1,0]"
      : "=v"(d) : "v"(a), "v"(b), "v"(c));
  return d;
}

__device__ __forceinline__ v2f shfl2(v2f v, int m) {
  v2f r;
  r.x = __shfl_xor(v.x, m, 64);
  r.y = __shfl_xor(v.y, m, 64);
  return r;
}

// KIND: 0=RX 1=RY 2=RZ. BT/BC: target/control bit of the amplitude index.
// cs = (cos(t/2), sin(t/2)).
template <int KIND, int BT, int BC>
__device__ __forceinline__ void crg(v2f w[4], v2f cs, int lane) {
  v2f K = cs;
  if constexpr (BC >= 2) {
    const bool on = (lane >> (BC - 2)) & 1;
    K.x = on ? K.x : 1.f;
    K.y = on ? K.y : 0.f;
  }
  if constexpr (BT >= 2 && KIND == 1) {  // ry: st = tb ? +s : -s
    const bool tb = (lane >> (BT - 2)) & 1;
    K.y = tb ? K.y : -K.y;
  }
  if constexpr (BT >= 2 && KIND == 2) {  // rz: st = tb ? -s : +s
    const bool tb = (lane >> (BT - 2)) & 1;
    K.y = tb ? -K.y : K.y;
  }
  if constexpr (KIND == 2) {  // diagonal: no partner
#pragma unroll
    for (int k = 0; k < 4; ++k) {
      const bool kon = (BC >= 2) || (((k >> BC) & 1) != 0);
      if (!kon) continue;
      const v2f t = pk_mul_s(K, w[k]);
      if constexpr (BT >= 2) {
        w[k] = pk_fma_rot(K, w[k], t);
      } else {
        if ((k >> BT) & 1)
          w[k] = pk_fma_irot(K, w[k], t);  // e^{+i}: (c*re - s*im, c*im + s*re)
        else
          w[k] = pk_fma_rot(K, w[k], t);   // e^{-i}: (c*re + s*im, c*im - s*re)
      }
    }
  } else if constexpr (BT >= 2) {
#pragma unroll
    for (int k = 0; k < 4; ++k) {
      const bool kon = (BC >= 2) || (((k >> BC) & 1) != 0);
      if (!kon) continue;
      const v2f p = shfl2(w[k], 1 << (BT - 2));
      const v2f t = pk_mul_s(K, w[k]);
      if constexpr (KIND == 0)
        w[k] = pk_fma_rot(K, p, t);  // c*w + s*(p.im, -p.re)
      else
        w[k] = pk_fma_shi(K, p, t);  // c*w + st*p
    }
  } else {
    v2f ow[4];
#pragma unroll
    for (int k = 0; k < 4; ++k) ow[k] = w[k];
#pragma unroll
    for (int k = 0; k < 4; ++k) {
      const bool kon = (BC >= 2) || (((k >> BC) & 1) != 0);
      if (!kon) continue;
      const v2f p = ow[k ^ (1 << BT)];
      const v2f t = pk_mul_s(K, ow[k]);
      if constexpr (KIND == 0) {
        w[k] = pk_fma_rot(K, p, t);
      } else {  // ry, per-k sign
        if ((k >> BT) & 1)
          w[k] = pk_fma_shi(K, p, t);
        else
          w[k] = pk_fma_shi_neg(K, p, t);
      }
    }
  }
}

// U[0]=(u00r,0) U[1]=(u01r,u01i) U[2]=(u10r,u10i) U[3]=(u11r,u11i)
template <int BT>
__device__ __forceinline__ void u3g(v2f w[4], const v2f U0, const v2f U1,
                                    const v2f U2, const v2f U3v, int lane) {
  if constexpr (BT >= 2) {
    const bool tb = (lane >> (BT - 2)) & 1;
    v2f A, Bq;
    A.x = tb ? U3v.x : U0.x;
    A.y = tb ? U3v.y : U0.y;
    Bq.x = tb ? U2.x : U1.x;
    Bq.y = tb ? U2.y : U1.y;
#pragma unroll
    for (int k = 0; k < 4; ++k) {
      const v2f p = shfl2(w[k], 1 << (BT - 2));
      v2f t = pk_mul_s(A, w[k]);      // (ar*wr, ar*wi)
      t = pk_fma_irot(A, w[k], t);    // += ai*(-wi, wr)
      t = pk_fma_slo(Bq, p, t);       // += br*(pr, pi)
      w[k] = pk_fma_irot(Bq, p, t);   // += bi*(-pi, pr)
    }
  } else {
    v2f ow[4];
#pragma unroll
    for (int k = 0; k < 4; ++k) ow[k] = w[k];
#pragma unroll
    for (int k = 0; k < 4; ++k) {
      const v2f p = ow[k ^ (1 << BT)];
      if (((k >> BT) & 1) == 0) {  // row0: u00 imag part is exactly 0
        v2f t = pk_mul_s(U0, ow[k]);
        t = pk_fma_slo(U1, p, t);
        w[k] = pk_fma_irot(U1, p, t);
      } else {
        v2f t = pk_mul_s(U3v, ow[k]);
        t = pk_fma_irot(U3v, ow[k], t);
        t = pk_fma_slo(U2, p, t);
        w[k] = pk_fma_irot(U2, p, t);
      }
    }
  }
}

__device__ __forceinline__ v2f ld2(const float* __restrict__ p) {
  return *(const v2f*)p;
}

template <int KIND>
__device__ __forceinline__ v2f run_branch(const float enc[4],
                                          const float* __restrict__ Gb,
                                          int lane) {
  v2f w[4];
#pragma unroll
  for (int k = 0; k < 4; ++k) { w[k].x = enc[k]; w[k].y = 0.f; }
  // CR_PAIRS_1: (0,1)(2,3)(4,5)(6,7)(1,2)(3,4)(5,6) -> <BT,BC>
  crg<KIND, 6, 7>(w, ld2(Gb + 0), lane);
  crg<KIND, 0, 5>(w, ld2(Gb + 8), lane);
  crg<KIND, 3, 4>(w, ld2(Gb + 16), lane);
  crg<KIND, 1, 2>(w, ld2(Gb + 24), lane);
  crg<KIND, 5, 6>(w, ld2(Gb + 32), lane);
  crg<KIND, 4, 0>(w, ld2(Gb + 40), lane);
  crg<KIND, 2, 3>(w, ld2(Gb + 48), lane);
  // U3 on wires 1,3,5,7 -> BT 6,0,3,1
  u3g<6>(w, ld2(Gb + 56), ld2(Gb + 58), ld2(Gb + 60), ld2(Gb + 62), lane);
  u3g<0>(w, ld2(Gb + 64), ld2(Gb + 66), ld2(Gb + 68), ld2(Gb + 70), lane);
  u3g<3>(w, ld2(Gb + 72), ld2(Gb + 74), ld2(Gb + 76), ld2(Gb + 78), lane);
  u3g<1>(w, ld2(Gb + 80), ld2(Gb + 82), ld2(Gb + 84), ld2(Gb + 86), lane);
  // CR_PAIRS_2: (1,3)(5,7)(3,5)
  crg<KIND, 0, 6>(w, ld2(Gb + 88), lane);
  crg<KIND, 1, 3>(w, ld2(Gb + 96), lane);
  crg<KIND, 3, 0>(w, ld2(Gb + 104), lane);
  // U3 on 3, then 7
  u3g<0>(w, ld2(Gb + 112), ld2(Gb + 114), ld2(Gb + 116), ld2(Gb + 118), lane);
  u3g<1>(w, ld2(Gb + 120), ld2(Gb + 122), ld2(Gb + 124), ld2(Gb + 126), lane);

  // expval_z(3) -> amp bit0, expval_z(7) -> amp bit1
  float pk[4];
#pragma unroll
  for (int k = 0; k < 4; ++k) pk[k] = w[k].x * w[k].x + w[k].y * w[k].y;
  v2f z;
  z.x = (pk[0] + pk[2]) - (pk[1] + pk[3]);
  z.y = (pk[0] + pk[1]) - (pk[2] + pk[3]);
#pragma unroll
  for (int m = 1; m < 64; m <<= 1) z += shfl2(z, m);
  return z;
}

// 48 gate slots x 8 floats: CR slots hold (c,s); U3 slots full 2x2 complex
__global__ void qcnn_prep(const float* __restrict__ crx, const float* __restrict__ u3x,
                          const float* __restrict__ cry, const float* __restrict__ u3y,
                          const float* __restrict__ crz, const float* __restrict__ u3z,
                          float* __restrict__ G) {
  const int tid = threadIdx.x;
  if (tid >= 48) return;
  const int br = tid >> 4;
  const int g = tid & 15;
  const float* crp = (br == 0) ? crx : (br == 1) ? cry : crz;
  const float* u3p = (br == 0) ? u3x : (br == 1) ? u3y : u3z;

  float m[8] = {0.f, 0.f, 0.f, 0.f, 0.f, 0.f, 0.f, 0.f};
  int u3i = -1;
  float th = 0.f;
  if (g < 7)
    th = crp[g];
  else if (g < 11)
    u3i = g - 7;
  else if (g < 14)
    th = crp[7 + (g - 11)];
  else
    u3i = 4 + (g - 14);

  if (u3i < 0) {
    float s, c;
    sincosf(0.5f * th, &s, &c);
    m[0] = c;
    m[1] = s;
  } else {
    const float t0 = u3p[u3i * 3 + 0];
    const float ph = u3p[u3i * 3 + 1];
    const float lm = u3p[u3i * 3 + 2];
    float st, ct, sp, cp, sl, cl;
    sincosf(0.5f * t0, &st, &ct);
    sincosf(ph, &sp, &cp);
    sincosf(lm, &sl, &cl);
    m[0] = ct;        m[1] = 0.f;
    m[2] = -cl * st;  m[3] = -sl * st;
    m[4] = cp * st;   m[5] = sp * st;
    const float cpl = cp * cl - sp * sl;
    const float spl_ = sp * cl + cp * sl;
    m[6] = cpl * ct;  m[7] = spl_ * ct;
  }
#pragma unroll
  for (int j = 0; j < 8; ++j) G[tid * 8 + j] = m[j];
}

__global__ __launch_bounds__(256) void qcnn_main(
    const float* __restrict__ x, const float* __restrict__ G,
    const float* __restrict__ w1, const float* __restrict__ b1,
    const float* __restrict__ w2, const float* __restrict__ b2,
    float* __restrict__ out, int B) {
  const int gtid = blockIdx.x * blockDim.x + threadIdx.x;
  const int b = gtid >> 6;
  const int lane = threadIdx.x & 63;
  if (b >= B) return;

  // hoist MLP weight loads to the top so VMEM latency hides under gate math
  const int j = (lane < 12) ? lane : 0;
  const float* w1r = w1 + j * 6;
  float w1v[6];
#pragma unroll
  for (int t = 0; t < 6; ++t) w1v[t] = w1r[t];
  const float b1v = b1[j];
  const float w2v = w2[j];
  const float b2v = b2[0];

  // ---- encode: product state, real amplitudes ----
  const float4* xv = reinterpret_cast<const float4*>(x + b * 8);
  const float4 xlo = xv[0], xhi = xv[1];
  const float xq[8] = {xlo.x, xlo.y, xlo.z, xlo.w, xhi.x, xhi.y, xhi.z, xhi.w};
  float sn[8], cs[8];
#pragma unroll
  for (int q = 0; q < 8; ++q) __sincosf(0.5f * xq[q], &sn[q], &cs[q]);
  float P = 1.f;
  {
    const int qH[6] = {0, 1, 2, 4, 5, 6};
    const int bH[6] = {7, 6, 5, 4, 3, 2};
#pragma unroll
    for (int t = 0; t < 6; ++t)
      P *= ((lane >> (bH[t] - 2)) & 1) ? sn[qH[t]] : cs[qH[t]];
  }
  float enc[4];
#pragma unroll
  for (int k = 0; k < 4; ++k)
    enc[k] = P * ((k & 1) ? sn[3] : cs[3]) * ((k & 2) ? sn[7] : cs[7]);

  const v2f fx = run_branch<0>(enc, G, lane);
  const v2f fy = run_branch<1>(enc, G + 128, lane);
  const v2f fz = run_branch<2>(enc, G + 256, lane);

  // ---- MLP head, lane-parallel over the 12 hidden units ----
  float a = b1v;
  a += w1v[0] * fx.x + w1v[1] * fx.y + w1v[2] * fy.x + w1v[3] * fy.y +
       w1v[4] * fz.x + w1v[5] * fz.y;
  const float e = __expf(2.f * a);
  const float th = 1.f - 2.f * __builtin_amdgcn_rcpf(e + 1.f);
  float t = (lane < 12) ? w2v * th : 0.f;
#pragma unroll
  for (int m = 1; m < 64; m <<= 1) t += __shfl_xor(t, m, 64);
  const float acc = t + b2v;
  const float res = __builtin_amdgcn_rcpf(1.f + __expf(-acc));
  if (lane == 0) out[b] = res;
}

extern "C" void kernel_launch(void* const* d_in, const int* in_sizes, int n_in,
                              void* d_out, int out_size, void* d_ws,
                              size_t ws_size, hipStream_t stream) {
  const float* x = (const float*)d_in[0];
  const float* crx = (const float*)d_in[1];
  const float* u3x = (const float*)d_in[2];
  const float* cry = (const float*)d_in[3];
  const float* u3y = (const float*)d_in[4];
  const float* crz = (const float*)d_in[5];
  const float* u3z = (const float*)d_in[6];
  const float* w1 = (const float*)d_in[7];
  const float* b1 = (const float*)d_in[8];
  const float* w2 = (const float*)d_in[9];
  const float* b2 = (const float*)d_in[10];
  float* out = (float*)d_out;
  float* G = (float*)d_ws;  // 384 floats
  const int B = in_sizes[0] / 8;

  hipLaunchKernelGGL(qcnn_prep, dim3(1), dim3(64), 0, stream, crx, u3x, cry,
                     u3y, crz, u3z, G);
  const int threads = 256;
  const int blocks = (B * 64 + threads - 1) / threads;
  hipLaunchKernelGGL(qcnn_main, dim3(blocks), dim3(threads), 0, stream, x, G,
                     w1, b1, w2, b2, out, B);
}

// Round 4
// 109.842 us; speedup vs baseline: 1.9158x; 1.2359x over previous
//
#include <hip/hip_runtime.h>
#include <math.h>

// ---------------------------------------------------------------------------
// QCNN_Diff R4: FOUR batch elements per wave (16 lanes each), 16 complex
// amps/lane. Amp index bits: slot s(4b) = in-lane, group-lane gl(4b) = lanes.
//   slot bits : q3->S0  q7->S1  q5->S2  q1->S3   (all U3/measured wires)
//   lane bits : q0->L0  q2->L1  q4->L2  q6->L3
// => all 6 U3 gates + CR_PAIRS_2 in-lane (no shuffle); only 3 CR gates per
// rx/ry branch cross-lane via single-instr ds_swizzle; rz branch shuffle-free.
// All gate math = VOP3P packed-fp32 inline asm (validated bit-exact in R3).
// ---------------------------------------------------------------------------

typedef float v2f __attribute__((ext_vector_type(2)));

// d = (a.lo*b.lo, a.lo*b.hi)
__device__ __forceinline__ v2f pk_mul_s(v2f a, v2f b) {
  v2f d;
  asm("v_pk_mul_f32 %0, %1, %2 op_sel:[0,0] op_sel_hi:[0,1]"
      : "=v"(d) : "v"(a), "v"(b));
  return d;
}
// d = (a.lo*b.lo + c.lo, a.lo*b.hi + c.hi)
__device__ __forceinline__ v2f pk_fma_slo(v2f a, v2f b, v2f c) {
  v2f d;
  asm("v_pk_fma_f32 %0, %1, %2, %3 op_sel:[0,0,0] op_sel_hi:[0,1,1]"
      : "=v"(d) : "v"(a), "v"(b), "v"(c));
  return d;
}
// d = (a.hi*b.lo + c.lo, a.hi*b.hi + c.hi)
__device__ __forceinline__ v2f pk_fma_shi(v2f a, v2f b, v2f c) {
  v2f d;
  asm("v_pk_fma_f32 %0, %1, %2, %3 op_sel:[1,0,0] op_sel_hi:[1,1,1]"
      : "=v"(d) : "v"(a), "v"(b), "v"(c));
  return d;
}
// d = (-a.hi*b.lo + c.lo, -a.hi*b.hi + c.hi)
__device__ __forceinline__ v2f pk_fma_shi_neg(v2f a, v2f b, v2f c) {
  v2f d;
  asm("v_pk_fma_f32 %0, %1, %2, %3 op_sel:[1,0,0] op_sel_hi:[1,1,1] neg_lo:[1,0,0] neg_hi:[1,0,0]"
      : "=v"(d) : "v"(a), "v"(b), "v"(c));
  return d;
}
// d = (a.hi*b.hi + c.lo, -a.hi*b.lo + c.hi)   -- "+s*(im,-re)" / e^{-i}
__device__ __forceinline__ v2f pk_fma_rot(v2f a, v2f b, v2f c) {
  v2f d;
  asm("v_pk_fma_f32 %0, %1, %2, %3 op_sel:[1,1,0] op_sel_hi:[1,0,1] neg_hi:[0,1,0]"
      : "=v"(d) : "v"(a), "v"(b), "v"(c));
  return d;
}
// d = (-a.hi*b.hi + c.lo, a.hi*b.lo + c.hi)   -- "+s*i*(re,im)" / e^{+i}
__device__ __forceinline__ v2f pk_fma_irot(v2f a, v2f b, v2f c) {
  v2f d;
  asm("v_pk_fma_f32 %0, %1, %2, %3 op_sel:[1,1,0] op_sel_hi:[1,0,1] neg_lo:[0,1,0]"
      : "=v"(d) : "v"(a), "v"(b), "v"(c));
  return d;
}

template <int MASK>
__device__ __forceinline__ float swz1(float v) {
  constexpr int pat = (MASK << 10) | 0x1F;  // xor-mode: new = lane ^ MASK
  return __int_as_float(
      __builtin_amdgcn_ds_swizzle(__float_as_int(v), pat));
}
template <int MASK>
__device__ __forceinline__ v2f swz2(v2f v) {
  v2f r;
  r.x = swz1<MASK>(v.x);
  r.y = swz1<MASK>(v.y);
  return r;
}

__device__ __forceinline__ v2f ld2(const float* __restrict__ p) {
  return *(const v2f*)p;
}

// ---- CR gate, control on lane bit LB, target on slot bit SB -----------------
template <int KIND, int LB, int SB>
__device__ __forceinline__ void cr_Lc_St(v2f w[16], v2f cs, int gl) {
  v2f K = cs;
  const bool on = (gl >> LB) & 1;
  K.x = on ? K.x : 1.f;
  K.y = on ? K.y : 0.f;
  if constexpr (KIND == 2) {  // rz: diagonal, per-slot sign compile-time
#pragma unroll
    for (int s = 0; s < 16; ++s) {
      const v2f t = pk_mul_s(K, w[s]);
      if (s & (1 << SB))
        w[s] = pk_fma_irot(K, w[s], t);
      else
        w[s] = pk_fma_rot(K, w[s], t);
    }
  } else {
#pragma unroll
    for (int s0 = 0; s0 < 16; ++s0) {
      if (s0 & (1 << SB)) continue;
      const int s1 = s0 | (1 << SB);
      const v2f a = w[s0], b = w[s1];
      if constexpr (KIND == 0) {  // rx: symmetric
        w[s0] = pk_fma_rot(K, b, pk_mul_s(K, a));
        w[s1] = pk_fma_rot(K, a, pk_mul_s(K, b));
      } else {  // ry
        w[s0] = pk_fma_shi_neg(K, b, pk_mul_s(K, a));
        w[s1] = pk_fma_shi(K, a, pk_mul_s(K, b));
      }
    }
  }
}

// ---- CR gate, control on slot bit SB, target on lane bit LB -----------------
template <int KIND, int SB, int LB>
__device__ __forceinline__ void cr_Sc_Lt(v2f w[16], v2f cs, int gl) {
  v2f K = cs;
  if constexpr (KIND == 1) {  // ry: st = tb ? +s : -s
    const bool tb = (gl >> LB) & 1;
    K.y = tb ? K.y : -K.y;
  }
  if constexpr (KIND == 2) {  // rz: st = tb ? -s : +s
    const bool tb = (gl >> LB) & 1;
    K.y = tb ? -K.y : K.y;
  }
#pragma unroll
  for (int s = 0; s < 16; ++s) {
    if (!(s & (1 << SB))) continue;  // control bit must be 1
    if constexpr (KIND == 2) {
      const v2f t = pk_mul_s(K, w[s]);
      w[s] = pk_fma_rot(K, w[s], t);
    } else {
      const v2f p = swz2<(1 << LB)>(w[s]);
      const v2f t = pk_mul_s(K, w[s]);
      if constexpr (KIND == 0)
        w[s] = pk_fma_rot(K, p, t);
      else
        w[s] = pk_fma_shi(K, p, t);
    }
  }
}

// ---- CR gate, control slot bit SBc, target slot bit SBt ---------------------
template <int KIND, int SBc, int SBt>
__device__ __forceinline__ void cr_Sc_St(v2f w[16], v2f cs) {
#pragma unroll
  for (int s0 = 0; s0 < 16; ++s0) {
    if (!(s0 & (1 << SBc))) continue;
    if (s0 & (1 << SBt)) continue;
    const int s1 = s0 | (1 << SBt);
    if constexpr (KIND == 2) {
      const v2f t0 = pk_mul_s(cs, w[s0]);
      w[s0] = pk_fma_rot(cs, w[s0], t0);  // target bit 0 -> e^{-i}
      const v2f t1 = pk_mul_s(cs, w[s1]);
      w[s1] = pk_fma_irot(cs, w[s1], t1);  // target bit 1 -> e^{+i}
    } else {
      const v2f a = w[s0], b = w[s1];
      if constexpr (KIND == 0) {
        w[s0] = pk_fma_rot(cs, b, pk_mul_s(cs, a));
        w[s1] = pk_fma_rot(cs, a, pk_mul_s(cs, b));
      } else {
        w[s0] = pk_fma_shi_neg(cs, b, pk_mul_s(cs, a));
        w[s1] = pk_fma_shi(cs, a, pk_mul_s(cs, b));
      }
    }
  }
}

// ---- U3 gate on slot bit SB. U0=(u00r,0) U1=u01 U2=u10 U3v=u11 --------------
template <int SB>
__device__ __forceinline__ void u3_St(v2f w[16], v2f U0, v2f U1, v2f U2,
                                      v2f U3v) {
#pragma unroll
  for (int s0 = 0; s0 < 16; ++s0) {
    if (s0 & (1 << SB)) continue;
    const int s1 = s0 | (1 << SB);
    const v2f a = w[s0], b = w[s1];
    // row0 (u00 real): u00*a + u01*b  -> 3 pk
    v2f t = pk_mul_s(U0, a);
    t = pk_fma_slo(U1, b, t);
    w[s0] = pk_fma_irot(U1, b, t);
    // row1: u11*b + u10*a -> 4 pk
    v2f u = pk_mul_s(U3v, b);
    u = pk_fma_irot(U3v, b, u);
    u = pk_fma_slo(U2, a, u);
    w[s1] = pk_fma_irot(U2, a, u);
  }
}

template <int KIND>
__device__ __forceinline__ v2f run_branch(const float Pa[4], const float b51[4],
                                          const float* __restrict__ Gb,
                                          int gl) {
  v2f w[16];
#pragma unroll
  for (int s = 0; s < 16; ++s) {
    w[s].x = Pa[s & 3] * b51[s >> 2];
    w[s].y = 0.f;
  }
  // CR_PAIRS_1: (0,1)(2,3)(4,5)(6,7) lane-ctrl; (1,2)(3,4)(5,6) slot-ctrl
  cr_Lc_St<KIND, 0, 3>(w, ld2(Gb + 0), gl);
  cr_Lc_St<KIND, 1, 0>(w, ld2(Gb + 8), gl);
  cr_Lc_St<KIND, 2, 2>(w, ld2(Gb + 16), gl);
  cr_Lc_St<KIND, 3, 1>(w, ld2(Gb + 24), gl);
  cr_Sc_Lt<KIND, 3, 1>(w, ld2(Gb + 32), gl);
  cr_Sc_Lt<KIND, 0, 2>(w, ld2(Gb + 40), gl);
  cr_Sc_Lt<KIND, 2, 3>(w, ld2(Gb + 48), gl);
  // U3 on wires 1,3,5,7 -> slot bits 3,0,2,1
  u3_St<3>(w, ld2(Gb + 56), ld2(Gb + 58), ld2(Gb + 60), ld2(Gb + 62));
  u3_St<0>(w, ld2(Gb + 64), ld2(Gb + 66), ld2(Gb + 68), ld2(Gb + 70));
  u3_St<2>(w, ld2(Gb + 72), ld2(Gb + 74), ld2(Gb + 76), ld2(Gb + 78));
  u3_St<1>(w, ld2(Gb + 80), ld2(Gb + 82), ld2(Gb + 84), ld2(Gb + 86));
  // CR_PAIRS_2: (1,3)(5,7)(3,5) -> all in-lane
  cr_Sc_St<KIND, 3, 0>(w, ld2(Gb + 88));
  cr_Sc_St<KIND, 2, 1>(w, ld2(Gb + 96));
  cr_Sc_St<KIND, 0, 2>(w, ld2(Gb + 104));
  // final U3 on wire 3 (S0), wire 7 (S1)
  u3_St<0>(w, ld2(Gb + 112), ld2(Gb + 114), ld2(Gb + 116), ld2(Gb + 118));
  u3_St<1>(w, ld2(Gb + 120), ld2(Gb + 122), ld2(Gb + 124), ld2(Gb + 126));

  // expval_z(q3)->slot bit0, expval_z(q7)->slot bit1
  float p[16];
#pragma unroll
  for (int s = 0; s < 16; ++s)
    p[s] = __builtin_fmaf(w[s].x, w[s].x, w[s].y * w[s].y);
  float g[4];
#pragma unroll
  for (int j = 0; j < 4; ++j)
    g[j] = (p[j] + p[j + 4]) + (p[j + 8] + p[j + 12]);
  float z3 = (g[0] + g[2]) - (g[1] + g[3]);
  float z7 = (g[0] + g[1]) - (g[2] + g[3]);
  // butterfly across the element's 16 lanes
  z3 += swz1<1>(z3); z7 += swz1<1>(z7);
  z3 += swz1<2>(z3); z7 += swz1<2>(z7);
  z3 += swz1<4>(z3); z7 += swz1<4>(z7);
  z3 += swz1<8>(z3); z7 += swz1<8>(z7);
  v2f r;
  r.x = z3;
  r.y = z7;
  return r;
}

// 48 gate slots x 8 floats: CR slots hold (c,s); U3 slots full 2x2 complex
__global__ void qcnn_prep(const float* __restrict__ crx, const float* __restrict__ u3x,
                          const float* __restrict__ cry, const float* __restrict__ u3y,
                          const float* __restrict__ crz, const float* __restrict__ u3z,
                          float* __restrict__ G) {
  const int tid = threadIdx.x;
  if (tid >= 48) return;
  const int br = tid >> 4;
  const int g = tid & 15;
  const float* crp = (br == 0) ? crx : (br == 1) ? cry : crz;
  const float* u3p = (br == 0) ? u3x : (br == 1) ? u3y : u3z;

  float m[8] = {0.f, 0.f, 0.f, 0.f, 0.f, 0.f, 0.f, 0.f};
  int u3i = -1;
  float th = 0.f;
  if (g < 7)
    th = crp[g];
  else if (g < 11)
    u3i = g - 7;
  else if (g < 14)
    th = crp[7 + (g - 11)];
  else
    u3i = 4 + (g - 14);

  if (u3i < 0) {
    float s, c;
    sincosf(0.5f * th, &s, &c);
    m[0] = c;
    m[1] = s;
  } else {
    const float t0 = u3p[u3i * 3 + 0];
    const float ph = u3p[u3i * 3 + 1];
    const float lm = u3p[u3i * 3 + 2];
    float st, ct, sp, cp, sl, cl;
    sincosf(0.5f * t0, &st, &ct);
    sincosf(ph, &sp, &cp);
    sincosf(lm, &sl, &cl);
    m[0] = ct;        m[1] = 0.f;
    m[2] = -cl * st;  m[3] = -sl * st;
    m[4] = cp * st;   m[5] = sp * st;
    const float cpl = cp * cl - sp * sl;
    const float spl_ = sp * cl + cp * sl;
    m[6] = cpl * ct;  m[7] = spl_ * ct;
  }
#pragma unroll
  for (int j = 0; j < 8; ++j) G[tid * 8 + j] = m[j];
}

__global__ __launch_bounds__(256) void qcnn_main(
    const float* __restrict__ x, const float* __restrict__ G,
    const float* __restrict__ w1, const float* __restrict__ b1,
    const float* __restrict__ w2, const float* __restrict__ b2,
    float* __restrict__ out, int B) {
  const int gid = blockIdx.x * blockDim.x + threadIdx.x;
  const int b = gid >> 4;  // one element per 16 consecutive threads
  const int gl = threadIdx.x & 15;
  if (b >= B) return;

  // hoist MLP weight loads so VMEM latency hides under gate math
  const int j = (gl < 12) ? gl : 0;
  const float* w1r = w1 + j * 6;
  float w1v[6];
#pragma unroll
  for (int t = 0; t < 6; ++t) w1v[t] = w1r[t];
  const float b1v = b1[j];
  const float w2v = w2[j];
  const float b2v = b2[0];

  // ---- encode ----
  const float4* xv = reinterpret_cast<const float4*>(x + b * 8);
  const float4 xlo = xv[0], xhi = xv[1];
  const float xq[8] = {xlo.x, xlo.y, xlo.z, xlo.w, xhi.x, xhi.y, xhi.z, xhi.w};
  float sn[8], cs_[8];
#pragma unroll
  for (int q = 0; q < 8; ++q) __sincosf(0.5f * xq[q], &sn[q], &cs_[q]);
  // lane-bit qubits: q0->L0 q2->L1 q4->L2 q6->L3
  const float P = (((gl >> 0) & 1) ? sn[0] : cs_[0]) *
                  (((gl >> 1) & 1) ? sn[2] : cs_[2]) *
                  (((gl >> 2) & 1) ? sn[4] : cs_[4]) *
                  (((gl >> 3) & 1) ? sn[6] : cs_[6]);
  // slot factors: bit0=q3 bit1=q7 (low pair), bit2=q5 bit3=q1 (high pair)
  float Pa[4], b51[4];
  Pa[0] = P * (cs_[3] * cs_[7]);
  Pa[1] = P * (sn[3] * cs_[7]);
  Pa[2] = P * (cs_[3] * sn[7]);
  Pa[3] = P * (sn[3] * sn[7]);
  b51[0] = cs_[5] * cs_[1];
  b51[1] = sn[5] * cs_[1];
  b51[2] = cs_[5] * sn[1];
  b51[3] = sn[5] * sn[1];

  const v2f fx = run_branch<0>(Pa, b51, G, gl);
  const v2f fy = run_branch<1>(Pa, b51, G + 128, gl);
  const v2f fz = run_branch<2>(Pa, b51, G + 256, gl);

  // ---- MLP head, lane-parallel over 12 hidden units within each 16-group ---
  float a = b1v;
  a += w1v[0] * fx.x + w1v[1] * fx.y + w1v[2] * fy.x + w1v[3] * fy.y +
       w1v[4] * fz.x + w1v[5] * fz.y;
  const float e = __expf(2.f * a);
  const float th = 1.f - 2.f * __builtin_amdgcn_rcpf(e + 1.f);
  float t = (gl < 12) ? w2v * th : 0.f;
  t += swz1<1>(t);
  t += swz1<2>(t);
  t += swz1<4>(t);
  t += swz1<8>(t);
  const float acc = t + b2v;
  const float res = __builtin_amdgcn_rcpf(1.f + __expf(-acc));
  if (gl == 0) out[b] = res;
}

extern "C" void kernel_launch(void* const* d_in, const int* in_sizes, int n_in,
                              void* d_out, int out_size, void* d_ws,
                              size_t ws_size, hipStream_t stream) {
  const float* x = (const float*)d_in[0];
  const float* crx = (const float*)d_in[1];
  const float* u3x = (const float*)d_in[2];
  const float* cry = (const float*)d_in[3];
  const float* u3y = (const float*)d_in[4];
  const float* crz = (const float*)d_in[5];
  const float* u3z = (const float*)d_in[6];
  const float* w1 = (const float*)d_in[7];
  const float* b1 = (const float*)d_in[8];
  const float* w2 = (const float*)d_in[9];
  const float* b2 = (const float*)d_in[10];
  float* out = (float*)d_out;
  float* G = (float*)d_ws;  // 384 floats
  const int B = in_sizes[0] / 8;

  hipLaunchKernelGGL(qcnn_prep, dim3(1), dim3(64), 0, stream, crx, u3x, cry,
                     u3y, crz, u3z, G);
  const int threads = 256;
  const int blocks = (B * 16 + threads - 1) / threads;
  hipLaunchKernelGGL(qcnn_main, dim3(blocks), dim3(threads), 0, stream, x, G,
                     w1, b1, w2, b2, out, B);
}

// Round 5
// 108.677 us; speedup vs baseline: 1.9363x; 1.0107x over previous
//
#include <hip/hip_runtime.h>
#include <math.h>

// ---------------------------------------------------------------------------
// QCNN_Diff R5: 4 elements/wave (16 lanes each), 16 complex amps/lane (v2f).
// Circuit compiled at prep time:
//  - Layer-1 CR gates (0,1)(2,3)(4,5)(6,7) folded into the product-state
//    build: w = v01 (x) v23 (x) v45 (x) v67, v = CR.(a(x)a).
//  - CR(1,3) fused into U3first(3): slot-selected matrices {U, R.U} (ctrl S3).
//  - CR(5,7)+U3first(7)+U3final(7) fused: {Uf.U, Uf.R.U} (ctrl S2).
// Remaining per branch: 3 cr_Sc_Lt (swizzle), 4 u3 gates, CR(3,5), 1 u3.
// slot bits: q3->S0 q7->S1 q5->S2 q1->S3; lane bits: q0->L0 q2->L1 q4->L2 q6->L3
// ---------------------------------------------------------------------------

typedef float v2f __attribute__((ext_vector_type(2)));

__device__ __forceinline__ v2f mk2(float a, float b) { v2f r; r.x = a; r.y = b; return r; }

// d = (a.lo*b.lo, a.lo*b.hi)
__device__ __forceinline__ v2f pk_mul_s(v2f a, v2f b) {
  v2f d;
  asm("v_pk_mul_f32 %0, %1, %2 op_sel:[0,0] op_sel_hi:[0,1]"
      : "=v"(d) : "v"(a), "v"(b));
  return d;
}
// d = (a.lo*b.lo + c.lo, a.lo*b.hi + c.hi)
__device__ __forceinline__ v2f pk_fma_slo(v2f a, v2f b, v2f c) {
  v2f d;
  asm("v_pk_fma_f32 %0, %1, %2, %3 op_sel:[0,0,0] op_sel_hi:[0,1,1]"
      : "=v"(d) : "v"(a), "v"(b), "v"(c));
  return d;
}
// d = (a.hi*b.lo + c.lo, a.hi*b.hi + c.hi)
__device__ __forceinline__ v2f pk_fma_shi(v2f a, v2f b, v2f c) {
  v2f d;
  asm("v_pk_fma_f32 %0, %1, %2, %3 op_sel:[1,0,0] op_sel_hi:[1,1,1]"
      : "=v"(d) : "v"(a), "v"(b), "v"(c));
  return d;
}
// d = (-a.hi*b.lo + c.lo, -a.hi*b.hi + c.hi)
__device__ __forceinline__ v2f pk_fma_shi_neg(v2f a, v2f b, v2f c) {
  v2f d;
  asm("v_pk_fma_f32 %0, %1, %2, %3 op_sel:[1,0,0] op_sel_hi:[1,1,1] neg_lo:[1,0,0] neg_hi:[1,0,0]"
      : "=v"(d) : "v"(a), "v"(b), "v"(c));
  return d;
}
// d = (a.hi*b.hi + c.lo, -a.hi*b.lo + c.hi)   -- "+s*(im,-re)" / e^{-i}
__device__ __forceinline__ v2f pk_fma_rot(v2f a, v2f b, v2f c) {
  v2f d;
  asm("v_pk_fma_f32 %0, %1, %2, %3 op_sel:[1,1,0] op_sel_hi:[1,0,1] neg_hi:[0,1,0]"
      : "=v"(d) : "v"(a), "v"(b), "v"(c));
  return d;
}
// d = (-a.hi*b.hi + c.lo, a.hi*b.lo + c.hi)   -- "+s*i*(re,im)" / e^{+i}
__device__ __forceinline__ v2f pk_fma_irot(v2f a, v2f b, v2f c) {
  v2f d;
  asm("v_pk_fma_f32 %0, %1, %2, %3 op_sel:[1,1,0] op_sel_hi:[1,0,1] neg_lo:[0,1,0]"
      : "=v"(d) : "v"(a), "v"(b), "v"(c));
  return d;
}
// complex multiply: (ar*br-ai*bi, ar*bi+ai*br)
__device__ __forceinline__ v2f cmul(v2f a, v2f b) {
  return pk_fma_irot(a, b, pk_mul_s(a, b));
}

template <int MASK>
__device__ __forceinline__ float swz1(float v) {
  constexpr int pat = (MASK << 10) | 0x1F;  // xor-mode
  return __int_as_float(__builtin_amdgcn_ds_swizzle(__float_as_int(v), pat));
}
template <int MASK>
__device__ __forceinline__ v2f swz2(v2f v) {
  v2f r;
  r.x = swz1<MASK>(v.x);
  r.y = swz1<MASK>(v.y);
  return r;
}

__device__ __forceinline__ v2f ld2(const float* __restrict__ p) {
  return *(const v2f*)p;
}

// one u3 output row: ua*a + ub*b; A_REAL => ua.im==0 (3 pk instead of 4)
template <bool A_REAL>
__device__ __forceinline__ v2f u3row(v2f ua, v2f ub, v2f a, v2f b) {
  v2f t = pk_mul_s(ua, a);
  if constexpr (!A_REAL) t = pk_fma_irot(ua, a, t);
  t = pk_fma_slo(ub, b, t);
  return pk_fma_irot(ub, b, t);
}

// ---- CR gate, control on slot bit SB, target on lane bit LB -----------------
template <int KIND, int SB, int LB>
__device__ __forceinline__ void cr_Sc_Lt(v2f w[16], v2f cs, int gl) {
  v2f K = cs;
  if constexpr (KIND == 1) {  // ry: st = tb ? +s : -s
    const bool tb = (gl >> LB) & 1;
    K.y = tb ? K.y : -K.y;
  }
  if constexpr (KIND == 2) {  // rz: st = tb ? -s : +s
    const bool tb = (gl >> LB) & 1;
    K.y = tb ? -K.y : K.y;
  }
#pragma unroll
  for (int s = 0; s < 16; ++s) {
    if (!(s & (1 << SB))) continue;  // control bit must be 1
    if constexpr (KIND == 2) {
      const v2f t = pk_mul_s(K, w[s]);
      w[s] = pk_fma_rot(K, w[s], t);
    } else {
      const v2f p = swz2<(1 << LB)>(w[s]);
      const v2f t = pk_mul_s(K, w[s]);
      if constexpr (KIND == 0)
        w[s] = pk_fma_rot(K, p, t);
      else
        w[s] = pk_fma_shi(K, p, t);
    }
  }
}

// ---- CR gate, control slot bit SBc, target slot bit SBt ---------------------
template <int KIND, int SBc, int SBt>
__device__ __forceinline__ void cr_Sc_St(v2f w[16], v2f cs) {
#pragma unroll
  for (int s0 = 0; s0 < 16; ++s0) {
    if (!(s0 & (1 << SBc))) continue;
    if (s0 & (1 << SBt)) continue;
    const int s1 = s0 | (1 << SBt);
    if constexpr (KIND == 2) {
      const v2f t0 = pk_mul_s(cs, w[s0]);
      w[s0] = pk_fma_rot(cs, w[s0], t0);
      const v2f t1 = pk_mul_s(cs, w[s1]);
      w[s1] = pk_fma_irot(cs, w[s1], t1);
    } else {
      const v2f a = w[s0], b = w[s1];
      if constexpr (KIND == 0) {
        w[s0] = pk_fma_rot(cs, b, pk_mul_s(cs, a));
        w[s1] = pk_fma_rot(cs, a, pk_mul_s(cs, b));
      } else {
        w[s0] = pk_fma_shi_neg(cs, b, pk_mul_s(cs, a));
        w[s1] = pk_fma_shi(cs, a, pk_mul_s(cs, b));
      }
    }
  }
}

// ---- plain u3 on slot bit SB; matrix at p = {u00,u01,u10,u11} (u00 real) ----
template <int SB>
__device__ __forceinline__ void u3_apply(v2f w[16], const float* __restrict__ p) {
  const v2f M0 = ld2(p), M1 = ld2(p + 2), M2 = ld2(p + 4), M3 = ld2(p + 6);
#pragma unroll
  for (int s0 = 0; s0 < 16; ++s0) {
    if (s0 & (1 << SB)) continue;
    const int s1 = s0 | (1 << SB);
    const v2f a = w[s0], b = w[s1];
    w[s0] = u3row<true>(M0, M1, a, b);
    w[s1] = u3row<false>(M3, M2, b, a);
  }
}

// ---- slot-selected u3: ctrl slot bit CB chooses matrix M (0) or N (1) -------
// M00R: M's u00 is real. N is always general.
template <int SB, int CB, bool M00R>
__device__ __forceinline__ void u3_sel(v2f w[16], const float* __restrict__ pM,
                                       const float* __restrict__ pN) {
  const v2f M0 = ld2(pM), M1 = ld2(pM + 2), M2 = ld2(pM + 4), M3 = ld2(pM + 6);
  const v2f N0 = ld2(pN), N1 = ld2(pN + 2), N2 = ld2(pN + 4), N3 = ld2(pN + 6);
#pragma unroll
  for (int s0 = 0; s0 < 16; ++s0) {
    if (s0 & (1 << SB)) continue;
    const int s1 = s0 | (1 << SB);
    const v2f a = w[s0], b = w[s1];
    if ((s0 >> CB) & 1) {
      w[s0] = u3row<false>(N0, N1, a, b);
      w[s1] = u3row<false>(N3, N2, b, a);
    } else {
      w[s0] = u3row<M00R>(M0, M1, a, b);
      w[s1] = u3row<false>(M3, M2, b, a);
    }
  }
}

// ---- layer-1 pair values: v = CR.(a_c (x) a_t), indexed (ctrlbit<<1)|tgtbit -
// pp = {c_c*c_t, c_c*s_t, s_c*c_t, s_c*s_t}
template <int KIND>
__device__ __forceinline__ void pairvals(float c, float s, const float* pp,
                                         v2f out[4]) {
  out[0] = mk2(pp[0], 0.f);
  out[1] = mk2(pp[1], 0.f);
  const float u = pp[2], wv = pp[3];
  if constexpr (KIND == 0) {  // rx
    out[2] = mk2(c * u, -s * wv);
    out[3] = mk2(c * wv, -s * u);
  } else if constexpr (KIND == 1) {  // ry
    out[2] = mk2(c * u - s * wv, 0.f);
    out[3] = mk2(s * u + c * wv, 0.f);
  } else {  // rz
    out[2] = mk2(c * u, -s * u);
    out[3] = mk2(c * wv, s * wv);
  }
}

template <int KIND>
__device__ __forceinline__ v2f run_branch(const float pp[4][4],
                                          const float* __restrict__ Gb,
                                          int gl) {
  // ---- build w = v01 (x) v45 (x) v67 (x) v23 over slot bits ----
  v2f P01[4], P23[4], P45[4], P67[4];
  pairvals<KIND>(Gb[0], Gb[1], pp[0], P01);
  pairvals<KIND>(Gb[8], Gb[9], pp[1], P23);
  pairvals<KIND>(Gb[16], Gb[17], pp[2], P45);
  pairvals<KIND>(Gb[24], Gb[25], pp[3], P67);
  const bool l0 = gl & 1, l1 = (gl >> 1) & 1, l2 = (gl >> 2) & 1,
             l3 = (gl >> 3) & 1;
  v2f s01[2] = {l0 ? P01[2] : P01[0], l0 ? P01[3] : P01[1]};
  v2f s23[2] = {l1 ? P23[2] : P23[0], l1 ? P23[3] : P23[1]};
  v2f s45[2] = {l2 ? P45[2] : P45[0], l2 ? P45[3] : P45[1]};
  v2f s67[2] = {l3 ? P67[2] : P67[0], l3 ? P67[3] : P67[1]};
  v2f A[4], Bv[4];
  A[0] = cmul(s01[0], s45[0]);
  A[1] = cmul(s01[0], s45[1]);
  A[2] = cmul(s01[1], s45[0]);
  A[3] = cmul(s01[1], s45[1]);
  Bv[0] = cmul(s67[0], s23[0]);
  Bv[1] = cmul(s67[0], s23[1]);
  Bv[2] = cmul(s67[1], s23[0]);
  Bv[3] = cmul(s67[1], s23[1]);
  v2f w[16];
#pragma unroll
  for (int s = 0; s < 16; ++s) w[s] = cmul(A[s >> 2], Bv[s & 3]);

  // ---- layer-2 CR gates (1,2)(3,4)(5,6): ctrl slot, tgt lane ----
  cr_Sc_Lt<KIND, 3, 1>(w, ld2(Gb + 32), gl);
  cr_Sc_Lt<KIND, 0, 2>(w, ld2(Gb + 40), gl);
  cr_Sc_Lt<KIND, 2, 3>(w, ld2(Gb + 48), gl);
  // ---- U3 layer (with fusions) ----
  u3_apply<3>(w, Gb + 64);                 // U3(1)
  u3_sel<0, 3, true>(w, Gb + 72, Gb + 80); // U3(3) fused w/ CR(1,3), ctrl q1=S3
  u3_apply<2>(w, Gb + 88);                 // U3(5)
  u3_sel<1, 2, false>(w, Gb + 96, Gb + 104); // Uf7.[R57].U7, ctrl q5=S2
  // ---- CR(3,5) then final U3(3) ----
  cr_Sc_St<KIND, 0, 2>(w, ld2(Gb + 56));
  u3_apply<0>(w, Gb + 112);                // U3final(3)

  // expval_z(q3)->slot bit0, expval_z(q7)->slot bit1
  float p[16];
#pragma unroll
  for (int s = 0; s < 16; ++s)
    p[s] = __builtin_fmaf(w[s].x, w[s].x, w[s].y * w[s].y);
  float g[4];
#pragma unroll
  for (int j = 0; j < 4; ++j)
    g[j] = (p[j] + p[j + 4]) + (p[j + 8] + p[j + 12]);
  float z3 = (g[0] + g[2]) - (g[1] + g[3]);
  float z7 = (g[0] + g[1]) - (g[2] + g[3]);
  z3 += swz1<1>(z3); z7 += swz1<1>(z7);
  z3 += swz1<2>(z3); z7 += swz1<2>(z7);
  z3 += swz1<4>(z3); z7 += swz1<4>(z7);
  z3 += swz1<8>(z3); z7 += swz1<8>(z7);
  return mk2(z3, z7);
}

// ============================ prep ==========================================
struct c2 { float r, i; };
__device__ __forceinline__ c2 cmulh(c2 a, c2 b) {
  return {a.r * b.r - a.i * b.i, a.r * b.i + a.i * b.r};
}
__device__ __forceinline__ c2 caddh(c2 a, c2 b) { return {a.r + b.r, a.i + b.i}; }
__device__ void mat2mul(const c2 A[4], const c2 B[4], c2 C[4]) {
  C[0] = caddh(cmulh(A[0], B[0]), cmulh(A[1], B[2]));
  C[1] = caddh(cmulh(A[0], B[1]), cmulh(A[1], B[3]));
  C[2] = caddh(cmulh(A[2], B[0]), cmulh(A[3], B[2]));
  C[3] = caddh(cmulh(A[2], B[1]), cmulh(A[3], B[3]));
}
__device__ void u3m(const float* p, c2 M[4]) {
  float st, ct, sp, cp, sl, cl;
  sincosf(0.5f * p[0], &st, &ct);
  sincosf(p[1], &sp, &cp);
  sincosf(p[2], &sl, &cl);
  M[0] = {ct, 0.f};
  M[1] = {-cl * st, -sl * st};
  M[2] = {cp * st, sp * st};
  M[3] = {(cp * cl - sp * sl) * ct, (sp * cl + cp * sl) * ct};
}
__device__ void rmat(int kind, float th, c2 R[4]) {
  float s, c;
  sincosf(0.5f * th, &s, &c);
  if (kind == 0) {
    R[0] = {c, 0.f}; R[1] = {0.f, -s}; R[2] = {0.f, -s}; R[3] = {c, 0.f};
  } else if (kind == 1) {
    R[0] = {c, 0.f}; R[1] = {-s, 0.f}; R[2] = {s, 0.f}; R[3] = {c, 0.f};
  } else {
    R[0] = {c, -s}; R[1] = {0.f, 0.f}; R[2] = {0.f, 0.f}; R[3] = {c, s};
  }
}
__device__ void storeM(float* dst, const c2 M[4]) {
#pragma unroll
  for (int j = 0; j < 4; ++j) { dst[2 * j] = M[j].r; dst[2 * j + 1] = M[j].i; }
}

__global__ void qcnn_prep(const float* __restrict__ crx, const float* __restrict__ u3x,
                          const float* __restrict__ cry, const float* __restrict__ u3y,
                          const float* __restrict__ crz, const float* __restrict__ u3z,
                          float* __restrict__ G) {
  const int br = threadIdx.x;
  if (br >= 3) return;
  const float* crp = (br == 0) ? crx : (br == 1) ? cry : crz;
  const float* u3p = (br == 0) ? u3x : (br == 1) ? u3y : u3z;
  float* Gb = G + br * 128;

  // CR (c,s) slots 0-7: (0,1)(2,3)(4,5)(6,7)(1,2)(3,4)(5,6)(3,5)
  const int crIdx[8] = {0, 1, 2, 3, 4, 5, 6, 9};
#pragma unroll
  for (int i = 0; i < 8; ++i) {
    float s, c;
    sincosf(0.5f * crp[crIdx[i]], &s, &c);
    Gb[i * 8] = c;
    Gb[i * 8 + 1] = s;
  }
  c2 U1v[4], U3v[4], U5v[4], U7a[4], U7b[4], U3f[4], R[4], T[4], T2[4];
  u3m(u3p + 0, U1v);   // U3(1)
  u3m(u3p + 3, U3v);   // U3first(3)
  u3m(u3p + 6, U5v);   // U3(5)
  u3m(u3p + 9, U7a);   // U3first(7)
  u3m(u3p + 12, U3f);  // U3final(3)
  u3m(u3p + 15, U7b);  // U3final(7)
  storeM(Gb + 64, U1v);                  // slot 8
  storeM(Gb + 72, U3v);                  // slot 9  : fused13 M0
  rmat(br, crp[7], R);                   // CR(1,3) rotation
  mat2mul(R, U3v, T);
  storeM(Gb + 80, T);                    // slot 10 : fused13 M1 = R.U
  storeM(Gb + 88, U5v);                  // slot 11
  mat2mul(U7b, U7a, T);
  storeM(Gb + 96, T);                    // slot 12 : big7 M0 = Uf.U
  rmat(br, crp[8], R);                   // CR(5,7) rotation
  mat2mul(R, U7a, T);
  mat2mul(U7b, T, T2);
  storeM(Gb + 104, T2);                  // slot 13 : big7 M1 = Uf.R.U
  storeM(Gb + 112, U3f);                 // slot 14
}

// ============================ main ==========================================
__global__ __launch_bounds__(256) void qcnn_main(
    const float* __restrict__ x, const float* __restrict__ G,
    const float* __restrict__ w1, const float* __restrict__ b1,
    const float* __restrict__ w2, const float* __restrict__ b2,
    float* __restrict__ out, int B) {
  const int gid = blockIdx.x * blockDim.x + threadIdx.x;
  const int b = gid >> 4;  // one element per 16 consecutive threads
  const int gl = threadIdx.x & 15;
  if (b >= B) return;

  // ---- per-qubit-pair products pp[pair][(cbit<<1)|tbit] ----
  const float4* xv = reinterpret_cast<const float4*>(x + b * 8);
  const float4 xlo = xv[0], xhi = xv[1];
  const float xq[8] = {xlo.x, xlo.y, xlo.z, xlo.w, xhi.x, xhi.y, xhi.z, xhi.w};
  float sn[8], cs_[8];
#pragma unroll
  for (int q = 0; q < 8; ++q) __sincosf(0.5f * xq[q], &sn[q], &cs_[q]);
  float pp[4][4];
#pragma unroll
  for (int pr = 0; pr < 4; ++pr) {
    const int qc = 2 * pr, qt = 2 * pr + 1;
    pp[pr][0] = cs_[qc] * cs_[qt];
    pp[pr][1] = cs_[qc] * sn[qt];
    pp[pr][2] = sn[qc] * cs_[qt];
    pp[pr][3] = sn[qc] * sn[qt];
  }

  const v2f fx = run_branch<0>(pp, G, gl);
  const v2f fy = run_branch<1>(pp, G + 128, gl);
  const v2f fz = run_branch<2>(pp, G + 256, gl);

  // ---- MLP head, lane-parallel over 12 hidden units within each 16-group ---
  const int j = (gl < 12) ? gl : 0;
  const float* w1r = w1 + j * 6;
  float a = b1[j];
  a += w1r[0] * fx.x + w1r[1] * fx.y + w1r[2] * fy.x + w1r[3] * fy.y +
       w1r[4] * fz.x + w1r[5] * fz.y;
  const float e = __expf(2.f * a);
  const float th = 1.f - 2.f * __builtin_amdgcn_rcpf(e + 1.f);
  float t = (gl < 12) ? w2[j] * th : 0.f;
  t += swz1<1>(t);
  t += swz1<2>(t);
  t += swz1<4>(t);
  t += swz1<8>(t);
  const float acc = t + b2[0];
  const float res = __builtin_amdgcn_rcpf(1.f + __expf(-acc));
  if (gl == 0) out[b] = res;
}

extern "C" void kernel_launch(void* const* d_in, const int* in_sizes, int n_in,
                              void* d_out, int out_size, void* d_ws,
                              size_t ws_size, hipStream_t stream) {
  const float* x = (const float*)d_in[0];
  const float* crx = (const float*)d_in[1];
  const float* u3x = (const float*)d_in[2];
  const float* cry = (const float*)d_in[3];
  const float* u3y = (const float*)d_in[4];
  const float* crz = (const float*)d_in[5];
  const float* u3z = (const float*)d_in[6];
  const float* w1 = (const float*)d_in[7];
  const float* b1 = (const float*)d_in[8];
  const float* w2 = (const float*)d_in[9];
  const float* b2 = (const float*)d_in[10];
  float* out = (float*)d_out;
  float* G = (float*)d_ws;  // 384 floats
  const int B = in_sizes[0] / 8;

  hipLaunchKernelGGL(qcnn_prep, dim3(1), dim3(64), 0, stream, crx, u3x, cry,
                     u3y, crz, u3z, G);
  const int threads = 256;
  const int blocks = (B * 16 + threads - 1) / threads;
  hipLaunchKernelGGL(qcnn_main, dim3(blocks), dim3(threads), 0, stream, x, G,
                     w1, b1, w2, b2, out, B);
}

// Round 6
// 107.841 us; speedup vs baseline: 1.9513x; 1.0078x over previous
//
#include <hip/hip_runtime.h>
#include <math.h>

// ---------------------------------------------------------------------------
// QCNN_Diff R6: 4 elements/wave (16 lanes each), 16 complex amps/lane.
// Register-pressure release: all wave-uniform gate data enters VOP3P packed
// math through SGPR operands ("s" asm constraint, 1 scalar src per instr);
// encode recomputed per branch; __launch_bounds__(256,8) -> VGPR<=64 so all
// 8 waves/SIMD (exactly one generation for B=32768) stay resident.
// Branch heads specialized: rx complex tensor; ry fully REAL until first U3;
// rz: all 7 leading CRZ gates collapsed into linear phase form phi(s)=a+sum k_b
// (per-slot sincos on real product state). Final U3(3) folded into the
// measurement as a quadratic form (alpha,beta,gr,gi from prep); z7 is
// invariant under it.
// slot bits: q3->S0 q7->S1 q5->S2 q1->S3; lane bits: q0->L0 q2->L1 q4->L2 q6->L3
// ---------------------------------------------------------------------------

typedef float v2f __attribute__((ext_vector_type(2)));

__device__ __forceinline__ v2f mk2(float a, float b) { v2f r; r.x = a; r.y = b; return r; }
__device__ __forceinline__ v2f ld2(const float* __restrict__ p) { return *(const v2f*)p; }

// ---- VOP3P primitives, VGPR x VGPR (for data*data complex mul) -------------
__device__ __forceinline__ v2f pk_mul_s(v2f a, v2f b) { v2f d;
  asm("v_pk_mul_f32 %0, %1, %2 op_sel:[0,0] op_sel_hi:[0,1]" : "=v"(d) : "v"(a), "v"(b)); return d; }
__device__ __forceinline__ v2f pk_fma_irot(v2f a, v2f b, v2f c) { v2f d;
  asm("v_pk_fma_f32 %0, %1, %2, %3 op_sel:[1,1,0] op_sel_hi:[1,0,1] neg_lo:[0,1,0]" : "=v"(d) : "v"(a), "v"(b), "v"(c)); return d; }
__device__ __forceinline__ v2f cmul(v2f a, v2f b) { return pk_fma_irot(a, b, pk_mul_s(a, b)); }
// d = (a.hi*b.lo, a.lo*b.hi)  (measurement Im(a*conj(b)) helper)
__device__ __forceinline__ v2f pk_mul_swap(v2f a, v2f b) { v2f d;
  asm("v_pk_mul_f32 %0, %1, %2 op_sel:[1,0] op_sel_hi:[0,1]" : "=v"(d) : "v"(a), "v"(b)); return d; }

// ---- VOP3P primitives, SGPR (wave-uniform) first operand -------------------
__device__ __forceinline__ v2f pk_mul_sM(v2f M, v2f b) { v2f d;
  asm("v_pk_mul_f32 %0, %1, %2 op_sel:[0,0] op_sel_hi:[0,1]" : "=v"(d) : "s"(M), "v"(b)); return d; }
__device__ __forceinline__ v2f pk_fma_sloM(v2f M, v2f b, v2f c) { v2f d;
  asm("v_pk_fma_f32 %0, %1, %2, %3 op_sel:[0,0,0] op_sel_hi:[0,1,1]" : "=v"(d) : "s"(M), "v"(b), "v"(c)); return d; }
__device__ __forceinline__ v2f pk_fma_shiM(v2f M, v2f b, v2f c) { v2f d;
  asm("v_pk_fma_f32 %0, %1, %2, %3 op_sel:[1,0,0] op_sel_hi:[1,1,1]" : "=v"(d) : "s"(M), "v"(b), "v"(c)); return d; }
__device__ __forceinline__ v2f pk_fma_shi_negM(v2f M, v2f b, v2f c) { v2f d;
  asm("v_pk_fma_f32 %0, %1, %2, %3 op_sel:[1,0,0] op_sel_hi:[1,1,1] neg_lo:[1,0,0] neg_hi:[1,0,0]" : "=v"(d) : "s"(M), "v"(b), "v"(c)); return d; }
__device__ __forceinline__ v2f pk_fma_rotM(v2f M, v2f b, v2f c) { v2f d;
  asm("v_pk_fma_f32 %0, %1, %2, %3 op_sel:[1,1,0] op_sel_hi:[1,0,1] neg_hi:[0,1,0]" : "=v"(d) : "s"(M), "v"(b), "v"(c)); return d; }
__device__ __forceinline__ v2f pk_fma_irotM(v2f M, v2f b, v2f c) { v2f d;
  asm("v_pk_fma_f32 %0, %1, %2, %3 op_sel:[1,1,0] op_sel_hi:[1,0,1] neg_lo:[0,1,0]" : "=v"(d) : "s"(M), "v"(b), "v"(c)); return d; }

template <int MASK>
__device__ __forceinline__ float swz1(float v) {
  constexpr int pat = (MASK << 10) | 0x1F;  // xor-mode
  return __int_as_float(__builtin_amdgcn_ds_swizzle(__float_as_int(v), pat));
}
template <int MASK>
__device__ __forceinline__ v2f swz2(v2f v) {
  v2f r; r.x = swz1<MASK>(v.x); r.y = swz1<MASK>(v.y); return r;
}

// ---- u3 row: ua*a + ub*b, matrices from SGPRs ------------------------------
template <bool A_REAL>
__device__ __forceinline__ v2f u3row_s(v2f ua, v2f ub, v2f a, v2f b) {
  v2f t = pk_mul_sM(ua, a);
  if constexpr (!A_REAL) t = pk_fma_irotM(ua, a, t);
  t = pk_fma_sloM(ub, b, t);
  return pk_fma_irotM(ub, b, t);
}

template <int SB>
__device__ __forceinline__ void u3_apply(v2f w[16], const float* __restrict__ p) {
  const v2f M0 = ld2(p), M1 = ld2(p + 2), M2 = ld2(p + 4), M3 = ld2(p + 6);
#pragma unroll
  for (int s0 = 0; s0 < 16; ++s0) {
    if (s0 & (1 << SB)) continue;
    const int s1 = s0 | (1 << SB);
    const v2f a = w[s0], b = w[s1];
    w[s0] = u3row_s<true>(M0, M1, a, b);
    w[s1] = u3row_s<false>(M3, M2, b, a);
  }
}

template <int SB, int CB, bool M00R>
__device__ __forceinline__ void u3_sel(v2f w[16], const float* __restrict__ pM,
                                       const float* __restrict__ pN) {
  const v2f M0 = ld2(pM), M1 = ld2(pM + 2), M2 = ld2(pM + 4), M3 = ld2(pM + 6);
  const v2f N0 = ld2(pN), N1 = ld2(pN + 2), N2 = ld2(pN + 4), N3 = ld2(pN + 6);
#pragma unroll
  for (int s0 = 0; s0 < 16; ++s0) {
    if (s0 & (1 << SB)) continue;
    const int s1 = s0 | (1 << SB);
    const v2f a = w[s0], b = w[s1];
    if ((s0 >> CB) & 1) {
      w[s0] = u3row_s<false>(N0, N1, a, b);
      w[s1] = u3row_s<false>(N3, N2, b, a);
    } else {
      w[s0] = u3row_s<M00R>(M0, M1, a, b);
      w[s1] = u3row_s<false>(M3, M2, b, a);
    }
  }
}

// ---- rx CR, ctrl slot SB, tgt lane LB (coefficients uniform for rx) --------
template <int SB, int LB>
__device__ __forceinline__ void crx_Sc_Lt(v2f w[16], v2f cs) {
#pragma unroll
  for (int s = 0; s < 16; ++s) {
    if (!(s & (1 << SB))) continue;
    const v2f p = swz2<(1 << LB)>(w[s]);
    w[s] = pk_fma_rotM(cs, p, pk_mul_sM(cs, w[s]));
  }
}

// ---- ry CR on REAL state, ctrl slot SB, tgt lane LB ------------------------
template <int SB, int LB>
__device__ __forceinline__ void cr_ry_r(float w[16], v2f cs, int gl) {
  const bool tb = (gl >> LB) & 1;
  const float Ky = tb ? cs.y : -cs.y;
#pragma unroll
  for (int s = 0; s < 16; ++s) {
    if (!(s & (1 << SB))) continue;
    const float p = swz1<(1 << LB)>(w[s]);
    w[s] = __builtin_fmaf(Ky, p, cs.x * w[s]);
  }
}

// ---- CR ctrl slot SBc, tgt slot SBt ----------------------------------------
template <int KIND, int SBc, int SBt>
__device__ __forceinline__ void cr_Sc_St(v2f w[16], v2f cs) {
#pragma unroll
  for (int s0 = 0; s0 < 16; ++s0) {
    if (!(s0 & (1 << SBc))) continue;
    if constexpr (KIND == 2) {
      const v2f t = pk_mul_sM(cs, w[s0]);
      w[s0] = (s0 & (1 << SBt)) ? pk_fma_irotM(cs, w[s0], t)
                                : pk_fma_rotM(cs, w[s0], t);
    } else {
      if (s0 & (1 << SBt)) continue;
      const int s1 = s0 | (1 << SBt);
      const v2f a = w[s0], b = w[s1];
      if constexpr (KIND == 0) {
        w[s0] = pk_fma_rotM(cs, b, pk_mul_sM(cs, a));
        w[s1] = pk_fma_rotM(cs, a, pk_mul_sM(cs, b));
      } else {
        w[s0] = pk_fma_shi_negM(cs, b, pk_mul_sM(cs, a));
        w[s1] = pk_fma_shiM(cs, a, pk_mul_sM(cs, b));
      }
    }
  }
}

// ---- lift real state through u3 on slot bit SB -----------------------------
template <int SB>
__device__ __forceinline__ void u3_lift(v2f w[16], const float wr[16],
                                        const float* __restrict__ p) {
  const v2f M0 = ld2(p), M1 = ld2(p + 2), M2 = ld2(p + 4), M3 = ld2(p + 6);
#pragma unroll
  for (int s0 = 0; s0 < 16; ++s0) {
    if (s0 & (1 << SB)) continue;
    const int s1 = s0 | (1 << SB);
    const float a = wr[s0], b = wr[s1];
    w[s0] = mk2(__builtin_fmaf(a, M0.x, b * M1.x), b * M1.y);  // u00 imag==0
    w[s1] = mk2(__builtin_fmaf(a, M2.x, b * M3.x),
                __builtin_fmaf(a, M2.y, b * M3.y));
  }
}

// ---- measurement: final U3(3) folded into quadratic form -------------------
__device__ __forceinline__ v2f measure(v2f w[16], const float* __restrict__ q) {
  const v2f qa = ld2(q);      // (alpha, beta)
  const v2f qg = ld2(q + 2);  // (gr, gi)
  float z3a = 0.f, z3b = 0.f, z7p = 0.f, z7m = 0.f;
#pragma unroll
  for (int s0 = 0; s0 < 16; s0 += 2) {
    const v2f a = w[s0], b = w[s0 + 1];
    const v2f t1 = a * b, t2 = pk_mul_swap(a, b), t3 = a * a, t4 = b * b;
    const float r = t1.x + t1.y;
    const float m = t2.x - t2.y;
    const float na = t3.x + t3.y;
    const float nb = t4.x + t4.y;
    z3a = __builtin_fmaf(qa.x, na, z3a);
    z3b = __builtin_fmaf(qa.y, nb, z3b);
    z3a = __builtin_fmaf(qg.x, r, z3a);
    z3b = __builtin_fmaf(-qg.y, m, z3b);
    const float nn = na + nb;
    if (s0 & 2) z7m += nn; else z7p += nn;
  }
  float z3 = z3a + z3b, z7 = z7p - z7m;
  z3 += swz1<1>(z3); z7 += swz1<1>(z7);
  z3 += swz1<2>(z3); z7 += swz1<2>(z7);
  z3 += swz1<4>(z3); z7 += swz1<4>(z7);
  z3 += swz1<8>(z3); z7 += swz1<8>(z7);
  return mk2(z3, z7);
}

template <int KIND>
__device__ __forceinline__ v2f tail_common(v2f w[16], const float* __restrict__ Gb) {
  u3_sel<0, 3, true>(w, Gb + 72, Gb + 80);    // U3first(3) / R13.U3first(3)
  u3_apply<2>(w, Gb + 88);                    // U3(5)
  u3_sel<1, 2, false>(w, Gb + 96, Gb + 104);  // Uf7.U7 / Uf7.R57.U7
  cr_Sc_St<KIND, 0, 2>(w, ld2(Gb + 56));      // CR(3,5)
  return measure(w, Gb + 112);                // folds U3final(3)
}

__device__ __forceinline__ void load_sincos(const float* __restrict__ xb,
                                            float sn[8], float cn[8]) {
  const float4 xlo = ((const float4*)xb)[0];
  const float4 xhi = ((const float4*)xb)[1];
  const float xq[8] = {xlo.x, xlo.y, xlo.z, xlo.w, xhi.x, xhi.y, xhi.z, xhi.w};
#pragma unroll
  for (int q = 0; q < 8; ++q) __sincosf(0.5f * xq[q], &sn[q], &cn[q]);
}

// ============================ branch heads ==================================
__device__ v2f run_rx(const float* __restrict__ xb, const float* __restrict__ Gb,
                      int gl) {
  float sn[8], cn[8];
  load_sincos(xb, sn, cn);
  const bool l0 = gl & 1, l1 = (gl >> 1) & 1, l2 = (gl >> 2) & 1, l3 = (gl >> 3) & 1;
  v2f pa[4], pb[4];
#pragma unroll
  for (int pr = 0; pr < 4; ++pr) {
    const bool lh = (pr == 0) ? l0 : (pr == 1) ? l1 : (pr == 2) ? l2 : l3;
    const float c = Gb[pr * 8], s = Gb[pr * 8 + 1];
    const float uc = lh ? sn[2 * pr] : cn[2 * pr];
    const float b0 = uc * cn[2 * pr + 1], b1 = uc * sn[2 * pr + 1];
    const float Kx = lh ? c : 1.f;
    const float Kyn = lh ? -s : 0.f;
    pa[pr] = mk2(Kx * b0, Kyn * b1);
    pb[pr] = mk2(Kx * b1, Kyn * b0);
  }
  v2f A[4] = {cmul(pa[0], pa[2]), cmul(pa[0], pb[2]), cmul(pb[0], pa[2]), cmul(pb[0], pb[2])};
  v2f Bv[4] = {cmul(pa[3], pa[1]), cmul(pa[3], pb[1]), cmul(pb[3], pa[1]), cmul(pb[3], pb[1])};
  v2f w[16];
#pragma unroll
  for (int s = 0; s < 16; ++s) w[s] = cmul(A[s >> 2], Bv[s & 3]);
  crx_Sc_Lt<3, 1>(w, ld2(Gb + 32));  // (1,2)
  crx_Sc_Lt<0, 2>(w, ld2(Gb + 40));  // (3,4)
  crx_Sc_Lt<2, 3>(w, ld2(Gb + 48));  // (5,6)
  u3_apply<3>(w, Gb + 64);           // U3(1)
  return tail_common<0>(w, Gb);
}

__device__ v2f run_ry(const float* __restrict__ xb, const float* __restrict__ Gb,
                      int gl) {
  float sn[8], cn[8];
  load_sincos(xb, sn, cn);
  const bool l0 = gl & 1, l1 = (gl >> 1) & 1, l2 = (gl >> 2) & 1, l3 = (gl >> 3) & 1;
  float pa[4], pb[4];
#pragma unroll
  for (int pr = 0; pr < 4; ++pr) {
    const bool lh = (pr == 0) ? l0 : (pr == 1) ? l1 : (pr == 2) ? l2 : l3;
    const float c = Gb[pr * 8], s = Gb[pr * 8 + 1];
    const float uc = lh ? sn[2 * pr] : cn[2 * pr];
    const float b0 = uc * cn[2 * pr + 1], b1 = uc * sn[2 * pr + 1];
    const float Kx = lh ? c : 1.f;
    const float Ky = lh ? s : 0.f;
    pa[pr] = Kx * b0 - Ky * b1;
    pb[pr] = Ky * b0 + Kx * b1;
  }
  const float A[4] = {pa[0] * pa[2], pa[0] * pb[2], pb[0] * pa[2], pb[0] * pb[2]};
  const float Bv[4] = {pa[3] * pa[1], pa[3] * pb[1], pb[3] * pa[1], pb[3] * pb[1]};
  float wr[16];
#pragma unroll
  for (int s = 0; s < 16; ++s) wr[s] = A[s >> 2] * Bv[s & 3];
  cr_ry_r<3, 1>(wr, ld2(Gb + 32), gl);
  cr_ry_r<0, 2>(wr, ld2(Gb + 40), gl);
  cr_ry_r<2, 3>(wr, ld2(Gb + 48), gl);
  v2f w[16];
  u3_lift<3>(w, wr, Gb + 64);        // U3(1), real input
  return tail_common<1>(w, Gb);
}

__device__ v2f run_rz(const float* __restrict__ xb, const float* __restrict__ Gb,
                      int gl) {
  float sn[8], cn[8];
  load_sincos(xb, sn, cn);
  const bool l0 = gl & 1, l1 = (gl >> 1) & 1, l2 = (gl >> 2) & 1, l3 = (gl >> 3) & 1;
  // real product state (encode)
  const float u0 = l0 ? sn[0] : cn[0];
  const float u2 = l1 ? sn[2] : cn[2];
  const float u4 = l2 ? sn[4] : cn[4];
  const float u6 = l3 ? sn[6] : cn[6];
  const float P = (u0 * u2) * (u4 * u6);
  float v01[4], v23[4];  // v01[(s1<<1)|s0] = P*A3[s0]*A7[s1]; v23[(s3<<1)|s2] = A5[s2]*A1[s3]
  v01[0] = P * (cn[3] * cn[7]); v01[1] = P * (sn[3] * cn[7]);
  v01[2] = P * (cn[3] * sn[7]); v01[3] = P * (sn[3] * sn[7]);
  v23[0] = cn[5] * cn[1]; v23[1] = sn[5] * cn[1];
  v23[2] = cn[5] * sn[1]; v23[3] = sn[5] * sn[1];
  // 7 CRZ gates as linear phase form: phi(s) = aa + sum_b s_b * k_b
  const float t0 = Gb[2], h0 = Gb[3];
  const float t1 = Gb[10], h1 = Gb[11];
  const float t2 = Gb[18], h2 = Gb[19];
  const float t3 = Gb[26], h3 = Gb[27];
  const float h4 = Gb[35], h5 = Gb[43], h6 = Gb[51];
  const float kk[4] = {(l1 ? t1 : 0.f) + (l2 ? h5 : -h5),   // k0 (S0=q3)
                       (l3 ? t3 : 0.f),                      // k1 (S1=q7)
                       (l2 ? t2 : 0.f) + (l3 ? h6 : -h6),   // k2 (S2=q5)
                       (l0 ? t0 : 0.f) + (l1 ? h4 : -h4)};  // k3 (S3=q1)
  const float aa = -((l0 ? h0 : 0.f) + (l1 ? h1 : 0.f) + (l2 ? h2 : 0.f) + (l3 ? h3 : 0.f));
  float ph[16];
  ph[0] = aa;
#pragma unroll
  for (int bb = 0; bb < 4; ++bb) {
#pragma unroll
    for (int s = 0; s < (1 << bb); ++s) ph[s | (1 << bb)] = ph[s] + kk[bb];
  }
  v2f w[16];
#pragma unroll
  for (int s = 0; s < 16; ++s) {
    float sp, cp;
    __sincosf(ph[s], &sp, &cp);
    const float e = v01[s & 3] * v23[s >> 2];
    w[s] = mk2(e * cp, e * sp);
  }
  u3_apply<3>(w, Gb + 64);           // U3(1)
  return tail_common<2>(w, Gb);
}

// ============================ prep ==========================================
struct c2 { float r, i; };
__device__ __forceinline__ c2 cmulh(c2 a, c2 b) { return {a.r * b.r - a.i * b.i, a.r * b.i + a.i * b.r}; }
__device__ __forceinline__ c2 cmulc(c2 a, c2 b) { return {a.r * b.r + a.i * b.i, a.i * b.r - a.r * b.i}; }  // a*conj(b)
__device__ __forceinline__ c2 caddh(c2 a, c2 b) { return {a.r + b.r, a.i + b.i}; }
__device__ void mat2mul(const c2 A[4], const c2 B[4], c2 C[4]) {
  C[0] = caddh(cmulh(A[0], B[0]), cmulh(A[1], B[2]));
  C[1] = caddh(cmulh(A[0], B[1]), cmulh(A[1], B[3]));
  C[2] = caddh(cmulh(A[2], B[0]), cmulh(A[3], B[2]));
  C[3] = caddh(cmulh(A[2], B[1]), cmulh(A[3], B[3]));
}
__device__ void u3m(const float* p, c2 M[4]) {
  float st, ct, sp, cp, sl, cl;
  sincosf(0.5f * p[0], &st, &ct);
  sincosf(p[1], &sp, &cp);
  sincosf(p[2], &sl, &cl);
  M[0] = {ct, 0.f};
  M[1] = {-cl * st, -sl * st};
  M[2] = {cp * st, sp * st};
  M[3] = {(cp * cl - sp * sl) * ct, (sp * cl + cp * sl) * ct};
}
__device__ void rmat(int kind, float th, c2 R[4]) {
  float s, c;
  sincosf(0.5f * th, &s, &c);
  if (kind == 0) { R[0] = {c, 0.f}; R[1] = {0.f, -s}; R[2] = {0.f, -s}; R[3] = {c, 0.f}; }
  else if (kind == 1) { R[0] = {c, 0.f}; R[1] = {-s, 0.f}; R[2] = {s, 0.f}; R[3] = {c, 0.f}; }
  else { R[0] = {c, -s}; R[1] = {0.f, 0.f}; R[2] = {0.f, 0.f}; R[3] = {c, s}; }
}
__device__ void storeM(float* dst, const c2 M[4]) {
#pragma unroll
  for (int j = 0; j < 4; ++j) { dst[2 * j] = M[j].r; dst[2 * j + 1] = M[j].i; }
}

__global__ void qcnn_prep(const float* __restrict__ crx, const float* __restrict__ u3x,
                          const float* __restrict__ cry, const float* __restrict__ u3y,
                          const float* __restrict__ crz, const float* __restrict__ u3z,
                          float* __restrict__ G) {
  const int br = threadIdx.x;
  if (br >= 3) return;
  const float* crp = (br == 0) ? crx : (br == 1) ? cry : crz;
  const float* u3p = (br == 0) ? u3x : (br == 1) ? u3y : u3z;
  float* Gb = G + br * 128;

  // CR slots 0-7: (0,1)(2,3)(4,5)(6,7)(1,2)(3,4)(5,6)(3,5) -> (c,s, theta, theta/2)
  const int crIdx[8] = {0, 1, 2, 3, 4, 5, 6, 9};
#pragma unroll
  for (int i = 0; i < 8; ++i) {
    const float th = crp[crIdx[i]];
    float s, c;
    sincosf(0.5f * th, &s, &c);
    Gb[i * 8] = c;
    Gb[i * 8 + 1] = s;
    Gb[i * 8 + 2] = th;
    Gb[i * 8 + 3] = 0.5f * th;
  }
  c2 U1v[4], U3v[4], U5v[4], U7a[4], U7b[4], U3f[4], R[4], T[4], T2[4];
  u3m(u3p + 0, U1v);   // U3(1)
  u3m(u3p + 3, U3v);   // U3first(3)
  u3m(u3p + 6, U5v);   // U3(5)
  u3m(u3p + 9, U7a);   // U3first(7)
  u3m(u3p + 12, U3f);  // U3final(3)
  u3m(u3p + 15, U7b);  // U3final(7)
  storeM(Gb + 64, U1v);   // slot 8 : U3(1)
  storeM(Gb + 72, U3v);   // slot 9 : fused13 M
  rmat(br, crp[7], R);    // CR(1,3)
  mat2mul(R, U3v, T);
  storeM(Gb + 80, T);     // slot 10: fused13 N = R.U
  storeM(Gb + 88, U5v);   // slot 11: U3(5)
  mat2mul(U7b, U7a, T);
  storeM(Gb + 96, T);     // slot 12: big7 M = Uf.U
  rmat(br, crp[8], R);    // CR(5,7)
  mat2mul(R, U7a, T);
  mat2mul(U7b, T, T2);
  storeM(Gb + 104, T2);   // slot 13: big7 N = Uf.R.U
  // slot 14: measurement quadratic form of U3final(3)
  const float n00 = U3f[0].r * U3f[0].r + U3f[0].i * U3f[0].i;
  const float n01 = U3f[1].r * U3f[1].r + U3f[1].i * U3f[1].i;
  const float n10 = U3f[2].r * U3f[2].r + U3f[2].i * U3f[2].i;
  const float n11 = U3f[3].r * U3f[3].r + U3f[3].i * U3f[3].i;
  const c2 g01 = cmulc(U3f[0], U3f[1]);
  const c2 g23 = cmulc(U3f[2], U3f[3]);
  Gb[112] = n00 - n10;
  Gb[113] = n01 - n11;
  Gb[114] = 2.f * (g01.r - g23.r);
  Gb[115] = 2.f * (g01.i - g23.i);
}

// ============================ main ==========================================
__global__ __launch_bounds__(256, 8) void qcnn_main(
    const float* __restrict__ x, const float* __restrict__ G,
    const float* __restrict__ w1, const float* __restrict__ b1,
    const float* __restrict__ w2, const float* __restrict__ b2,
    float* __restrict__ out, int B) {
  const int gid = blockIdx.x * blockDim.x + threadIdx.x;
  const int b = gid >> 4;
  const int gl = threadIdx.x & 15;
  if (b >= B) return;
  const float* xb = x + b * 8;

  const v2f fx = run_rx(xb, G, gl);
  const v2f fy = run_ry(xb, G + 128, gl);
  const v2f fz = run_rz(xb, G + 256, gl);

  // MLP head, lane-parallel over 12 hidden units within each 16-group
  const int j = (gl < 12) ? gl : 0;
  const float* w1r = w1 + j * 6;
  float a = b1[j];
  a += w1r[0] * fx.x + w1r[1] * fx.y + w1r[2] * fy.x + w1r[3] * fy.y +
       w1r[4] * fz.x + w1r[5] * fz.y;
  const float e = __expf(2.f * a);
  const float th = 1.f - 2.f * __builtin_amdgcn_rcpf(e + 1.f);
  float t = (gl < 12) ? w2[j] * th : 0.f;
  t += swz1<1>(t);
  t += swz1<2>(t);
  t += swz1<4>(t);
  t += swz1<8>(t);
  const float acc = t + b2[0];
  const float res = __builtin_amdgcn_rcpf(1.f + __expf(-acc));
  if (gl == 0) out[b] = res;
}

extern "C" void kernel_launch(void* const* d_in, const int* in_sizes, int n_in,
                              void* d_out, int out_size, void* d_ws,
                              size_t ws_size, hipStream_t stream) {
  const float* x = (const float*)d_in[0];
  const float* crx = (const float*)d_in[1];
  const float* u3x = (const float*)d_in[2];
  const float* cry = (const float*)d_in[3];
  const float* u3y = (const float*)d_in[4];
  const float* crz = (const float*)d_in[5];
  const float* u3z = (const float*)d_in[6];
  const float* w1 = (const float*)d_in[7];
  const float* b1 = (const float*)d_in[8];
  const float* w2 = (const float*)d_in[9];
  const float* b2 = (const float*)d_in[10];
  float* out = (float*)d_out;
  float* G = (float*)d_ws;  // 384 floats
  const int B = in_sizes[0] / 8;

  hipLaunchKernelGGL(qcnn_prep, dim3(1), dim3(64), 0, stream, crx, u3x, cry,
                     u3y, crz, u3z, G);
  const int threads = 256;
  const int blocks = (B * 16 + threads - 1) / threads;
  hipLaunchKernelGGL(qcnn_main, dim3(blocks), dim3(threads), 0, stream, x, G,
                     w1, b1, w2, b2, out, B);
}